// Round 7
// baseline (2176.723 us; speedup 1.0000x reference)
//
#include <hip/hip_runtime.h>
#include <math.h>

typedef unsigned short u16;
typedef short short8 __attribute__((ext_vector_type(8)));
typedef float floatx4 __attribute__((ext_vector_type(4)));

__device__ __forceinline__ u16 f2bf(float f) {
  unsigned int u = __float_as_uint(f);
  u += 0x7fffu + ((u >> 16) & 1u);
  return (u16)(u >> 16);
}

// async 16B global->LDS (DMA; LDS dest = wave-uniform base + lane*16)
__device__ __forceinline__ void gld_lds16(const void* g, void* l) {
  __builtin_amdgcn_global_load_lds(
      (__attribute__((address_space(1))) void*)(g),
      (__attribute__((address_space(3))) void*)(l), 16, 0, 0);
}

// ---------------------------------------------------------------------------
// Batched transpose + f32->bf16 convert for all 5 weights: W[K][N] -> Wt[N][K]
// ---------------------------------------------------------------------------
__global__ __launch_bounds__(256) void transpose_all(
    const float* __restrict__ W0, u16* __restrict__ T0,
    const float* __restrict__ W1, u16* __restrict__ T1,
    const float* __restrict__ W2, u16* __restrict__ T2,
    const float* __restrict__ W3, u16* __restrict__ T3,
    const float* __restrict__ W4, u16* __restrict__ T4)
{
  int bid = blockIdx.x;
  const float* W; u16* Wt; int K, N, lb;
  if (bid < 3072)       { W = W0; Wt = T0; K = 1024; N = 3072;  lb = bid;         }
  else if (bid < 4096)  { W = W1; Wt = T1; K = 1024; N = 1024;  lb = bid - 3072;  }
  else if (bid < 8192)  { W = W2; Wt = T2; K = 1024; N = 4096;  lb = bid - 4096;  }
  else if (bid < 12288) { W = W3; Wt = T3; K = 4096; N = 1024;  lb = bid - 8192;  }
  else                  { W = W4; Wt = T4; K = 1024; N = 32000; lb = bid - 12288; }
  int nbx = N >> 5;
  int bx = lb % nbx, by = lb / nbx;

  __shared__ float tile[32][33];
  int tx = threadIdx.x & 31, ty = threadIdx.x >> 5;
  int n0 = bx * 32, k0 = by * 32;
#pragma unroll
  for (int i = 0; i < 4; i++)
    tile[ty + i * 8][tx] = W[(size_t)(k0 + ty + i * 8) * N + n0 + tx];
  __syncthreads();
#pragma unroll
  for (int i = 0; i < 4; i++)
    Wt[(size_t)(n0 + ty + i * 8) * K + k0 + tx] = f2bf(tile[tx][ty + i * 8]);
}

// ---------------------------------------------------------------------------
// Embedding
// ---------------------------------------------------------------------------
__global__ __launch_bounds__(256) void embed_kernel(
    const int* __restrict__ X, const float* __restrict__ tok,
    const float* __restrict__ pos, float* __restrict__ x, u16* __restrict__ xbf)
{
  int bs = blockIdx.x, t = threadIdx.x;
  int id = X[bs];
  int s = bs & 1023;
  float4 tv = *(const float4*)(tok + (size_t)id * 1024 + t * 4);
  float4 pv = *(const float4*)(pos + (size_t)s * 1024 + t * 4);
  float4 o;
  o.x = tv.x + pv.x; o.y = tv.y + pv.y; o.z = tv.z + pv.z; o.w = tv.w + pv.w;
  *(float4*)(x + (size_t)bs * 1024 + t * 4) = o;
  ushort4 ob; ob.x = f2bf(o.x); ob.y = f2bf(o.y); ob.z = f2bf(o.z); ob.w = f2bf(o.w);
  *(ushort4*)(xbf + (size_t)bs * 1024 + t * 4) = ob;
}

// ---------------------------------------------------------------------------
// MFMA GEMM, m97-style: C[M][N] = A[M][K] @ Bt[N][K]^T + bias.
// 32 KiB LDS -> 3-5 blocks/CU of TLP (R5 post-mortem: the 256^2 8-phase at
// 1 blk/CU was latency-bound at 684 TF on the head shape; this structure
// measured 773-912 TF in streamed-B regimes).
// mode 0: C f32.  mode 1: C bf16 + exact GELU.
// mode 2: C f32 + per-(row, BN-col-block) softmax partials (max, sumexp).
// mode 4: QKV fused epilogue — Q/K bf16 into C (layout [s][3072]); V
//         scattered transposed into VTout[bh][64][1024] (8-B stores).
// ---------------------------------------------------------------------------
template<int BM, int WGC, int WTR, int WTC>
__global__ __launch_bounds__(256) void gemm_mfma(
    const u16* __restrict__ A, const u16* __restrict__ Bt,
    const float* __restrict__ bias, void* __restrict__ Cout,
    float2* __restrict__ partial, u16* __restrict__ VTout,
    int M, int N, int K, int mode)
{
  constexpr int BN = WGC * WTC * 16;
  static_assert(BN == 128, "BN must be 128");
  __shared__ alignas(16) u16 As[BM * 64];
  __shared__ alignas(16) u16 Bs[128 * 64];

  const int t = threadIdx.x;
  const int wv = t >> 6, lane = t & 63;
  const int quad = lane >> 4, l16 = lane & 15;
  const int bx = blockIdx.x, by = blockIdx.y;
  const int row0 = by * BM, col0 = bx * BN;
  const int wr = (wv / WGC) * (WTR * 16);
  const int wc = (wv % WGC) * (WTC * 16);
  const int wcid = wv % WGC;

  floatx4 acc[WTR][WTC];
#pragma unroll
  for (int i = 0; i < WTR; i++)
#pragma unroll
    for (int j = 0; j < WTC; j++) acc[i][j] = (floatx4){0.f, 0.f, 0.f, 0.f};

  // staging geometry: chunk = 8 rows x 64 cols (1 KB). lane -> (row, swizzled col)
  const int srow = lane >> 3;                 // row within chunk
  const int scol = ((lane & 7) ^ srow) * 8;   // XOR-swizzled column group
  const int swz = l16 & 7;                    // fragment-read swizzle key

  const u16* Abase = A + (size_t)row0 * K;
  const u16* Bbase = Bt + (size_t)col0 * K;
  constexpr int CA = BM / 32;  // A chunks per wave
  constexpr int CB = 4;        // B chunks per wave

  for (int k0 = 0; k0 < K; k0 += 64) {
#pragma unroll
    for (int i = 0; i < CA; i++) {
      int chunk = wv * CA + i;
      gld_lds16(Abase + (size_t)(chunk * 8 + srow) * K + k0 + scol, &As[chunk * 512]);
    }
#pragma unroll
    for (int i = 0; i < CB; i++) {
      int chunk = wv * CB + i;
      gld_lds16(Bbase + (size_t)(chunk * 8 + srow) * K + k0 + scol, &Bs[chunk * 512]);
    }
    __syncthreads();
#pragma unroll
    for (int ks = 0; ks < 64; ks += 32) {
      const int g = quad | (ks >> 3);          // global column group 0..7
      const int cofs = ((g ^ swz) * 8);        // swizzled LDS column
      short8 a[WTR], b[WTC];
#pragma unroll
      for (int i = 0; i < WTR; i++)
        a[i] = *(const short8*)&As[(wr + i * 16 + l16) * 64 + cofs];
#pragma unroll
      for (int j = 0; j < WTC; j++)
        b[j] = *(const short8*)&Bs[(wc + j * 16 + l16) * 64 + cofs];
#pragma unroll
      for (int i = 0; i < WTR; i++)
#pragma unroll
        for (int j = 0; j < WTC; j++)
          acc[i][j] = __builtin_amdgcn_mfma_f32_16x16x32_bf16(a[i], b[j], acc[i][j], 0, 0, 0);
    }
    __syncthreads();
  }

  // ---- epilogue ----
  float bvj[WTC];
#pragma unroll
  for (int j = 0; j < WTC; j++) bvj[j] = bias[col0 + wc + j * 16 + l16];

  if (mode == 2) {
    // f32 store + per-row (max, sumexp) partials over this block's BN cols.
    // LDS reuse of As (K-loop done, post-barrier): redm/reds BM*WGC floats.
    float* redm = (float*)As;
    float* reds = redm + BM * WGC;
#pragma unroll
    for (int i = 0; i < WTR; i++) {
      int rloc = wr + i * 16 + quad * 4;
      int rbase = row0 + rloc;
#pragma unroll
      for (int r = 0; r < 4; r++) {
        float vv[WTC];
        float mx = -3.0e38f;
#pragma unroll
        for (int j = 0; j < WTC; j++) {
          int c = col0 + wc + j * 16 + l16;
          float v = acc[i][j][r] + bvj[j];
          vv[j] = v;
          ((float*)Cout)[(size_t)(rbase + r) * N + c] = v;
          mx = fmaxf(mx, v);
        }
#pragma unroll
        for (int off = 1; off < 16; off <<= 1) mx = fmaxf(mx, __shfl_xor(mx, off, 64));
        float ss = 0.f;
#pragma unroll
        for (int j = 0; j < WTC; j++) ss += __expf(vv[j] - mx);
#pragma unroll
        for (int off = 1; off < 16; off <<= 1) ss += __shfl_xor(ss, off, 64);
        if (l16 == 0) {
          redm[(rloc + r) * WGC + wcid] = mx;
          reds[(rloc + r) * WGC + wcid] = ss;
        }
      }
    }
    __syncthreads();
    const int pnb = N / BN;
    for (int rr = t; rr < BM; rr += 256) {
      float M2 = redm[rr * WGC], S2 = reds[rr * WGC];
#pragma unroll
      for (int w = 1; w < WGC; w++) {
        float m2 = redm[rr * WGC + w], s2 = reds[rr * WGC + w];
        float mn = fmaxf(M2, m2);
        S2 = S2 * __expf(M2 - mn) + s2 * __expf(m2 - mn);
        M2 = mn;
      }
      partial[(size_t)(row0 + rr) * pnb + bx] = make_float2(M2, S2);
    }
  } else if (mode == 4) {
    // QKV: Q/K -> bf16 C in [s][3072] layout; V -> VTout[bh][64][1024]
#pragma unroll
    for (int i = 0; i < WTR; i++) {
      int rbase = row0 + wr + i * 16 + quad * 4;
#pragma unroll
      for (int j = 0; j < WTC; j++) {
        int c = col0 + wc + j * 16 + l16;
        int h = c / 192, within = c - h * 192;
        if (within < 128) {
#pragma unroll
          for (int r = 0; r < 4; r++)
            ((u16*)Cout)[(size_t)(rbase + r) * N + c] = f2bf(acc[i][j][r] + bvj[j]);
        } else {
          int d = within - 128;
          int bb = rbase >> 10, s0 = rbase & 1023;
          ushort4 ov;
          ov.x = f2bf(acc[i][j][0] + bvj[j]);
          ov.y = f2bf(acc[i][j][1] + bvj[j]);
          ov.z = f2bf(acc[i][j][2] + bvj[j]);
          ov.w = f2bf(acc[i][j][3] + bvj[j]);
          *(ushort4*)(VTout + ((size_t)(bb * 16 + h) * 64 + d) * 1024 + s0) = ov;
        }
      }
    }
  } else {
#pragma unroll
    for (int i = 0; i < WTR; i++) {
      int rbase = row0 + wr + i * 16 + quad * 4;
#pragma unroll
      for (int j = 0; j < WTC; j++) {
        int c = col0 + wc + j * 16 + l16;
#pragma unroll
        for (int r = 0; r < 4; r++) {
          float v = acc[i][j][r] + bvj[j];
          size_t idx = (size_t)(rbase + r) * N + c;
          if (mode == 0) {
            ((float*)Cout)[idx] = v;
          } else {  // mode 1: GELU bf16
            float gl = 0.5f * v * (1.f + erff(v * 0.70710678118f));
            ((u16*)Cout)[idx] = f2bf(gl);
          }
        }
      }
    }
  }
}

// ---------------------------------------------------------------------------
// Flash attention. Q/K read directly from qkvbuf bf16 [2048][3072]
// (per-lane 16-B segments, same coalescing class as the old packed layout);
// V^T from the dedicated VT buffer (written by QKV GEMM mode-4 epilogue).
// ---------------------------------------------------------------------------
__global__ __launch_bounds__(256) void flash_attn(
    const u16* __restrict__ qkv, const u16* __restrict__ VT,
    u16* __restrict__ out)
{
  __shared__ alignas(16) u16 Ps[64][72];
  int qt = (int)gridDim.x - 1 - (int)blockIdx.x;
  int h = blockIdx.y, b = blockIdx.z;
  int bh = b * 16 + h;
  int t = threadIdx.x;
  int wv = t >> 6, lane = t & 63, l16 = lane & 15, quad = lane >> 4;
  int qrow0 = qt * 64 + wv * 16;

  const u16* Qb = qkv + (size_t)b * 1024 * 3072 + h * 192;
  const u16* Kb = Qb + 64;
  const u16* Vb = VT + (size_t)bh * 64 * 1024;

  short8 qfrag[2];
  qfrag[0] = *(const short8*)(Qb + (size_t)(qrow0 + l16) * 3072 + quad * 8);
  qfrag[1] = *(const short8*)(Qb + (size_t)(qrow0 + l16) * 3072 + 32 + quad * 8);

  floatx4 accO[4];
#pragma unroll
  for (int i = 0; i < 4; i++) accO[i] = (floatx4){0.f, 0.f, 0.f, 0.f};
  float m[4], l[4];
#pragma unroll
  for (int r = 0; r < 4; r++) { m[r] = -3.0e38f; l[r] = 0.f; }

  for (int jt = 0; jt <= qt; jt++) {
    float sv[4][4];
    bool diag = (jt == qt);
#pragma unroll
    for (int nt = 0; nt < 4; nt++) {
      const u16* Kt = Kb + (size_t)(jt * 64 + nt * 16 + l16) * 3072;
      short8 b0 = *(const short8*)(Kt + quad * 8);
      short8 b1 = *(const short8*)(Kt + 32 + quad * 8);
      floatx4 acc = (floatx4){0.f, 0.f, 0.f, 0.f};
      acc = __builtin_amdgcn_mfma_f32_16x16x32_bf16(qfrag[0], b0, acc, 0, 0, 0);
      acc = __builtin_amdgcn_mfma_f32_16x16x32_bf16(qfrag[1], b1, acc, 0, 0, 0);
#pragma unroll
      for (int r = 0; r < 4; r++) {
        float v = acc[r] * 0.125f;
        if (diag) {
          int j = nt * 16 + l16;
          int q = wv * 16 + quad * 4 + r;
          if (j > q) v = -3.0e38f;
        }
        sv[nt][r] = v;
      }
    }
    float rm[4];
#pragma unroll
    for (int r = 0; r < 4; r++) {
      rm[r] = fmaxf(fmaxf(sv[0][r], sv[1][r]), fmaxf(sv[2][r], sv[3][r]));
#pragma unroll
      for (int off = 1; off < 16; off <<= 1)
        rm[r] = fmaxf(rm[r], __shfl_xor(rm[r], off, 64));
    }
    float al[4], rs[4];
    float p[4][4];
#pragma unroll
    for (int r = 0; r < 4; r++) {
      float mn = fmaxf(m[r], rm[r]);
      al[r] = __expf(m[r] - mn);
      m[r] = mn;
      rs[r] = 0.f;
    }
#pragma unroll
    for (int nt = 0; nt < 4; nt++)
#pragma unroll
      for (int r = 0; r < 4; r++) {
        float e = __expf(sv[nt][r] - m[r]);
        p[nt][r] = e;
        rs[r] += e;
      }
#pragma unroll
    for (int r = 0; r < 4; r++) {
#pragma unroll
      for (int off = 1; off < 16; off <<= 1)
        rs[r] += __shfl_xor(rs[r], off, 64);
      l[r] = l[r] * al[r] + rs[r];
    }
#pragma unroll
    for (int nt = 0; nt < 4; nt++)
#pragma unroll
      for (int r = 0; r < 4; r++) accO[nt][r] *= al[r];

    __syncthreads();
#pragma unroll
    for (int nt = 0; nt < 4; nt++)
#pragma unroll
      for (int r = 0; r < 4; r++)
        Ps[wv * 16 + quad * 4 + r][nt * 16 + l16] = f2bf(p[nt][r]);
    __syncthreads();

    short8 pf0 = *(const short8*)&Ps[wv * 16 + l16][quad * 8];
    short8 pf1 = *(const short8*)&Ps[wv * 16 + l16][32 + quad * 8];
#pragma unroll
    for (int nt = 0; nt < 4; nt++) {
      const u16* Vt = Vb + (size_t)(nt * 16 + l16) * 1024 + jt * 64;
      short8 v0 = *(const short8*)(Vt + quad * 8);
      short8 v1 = *(const short8*)(Vt + 32 + quad * 8);
      accO[nt] = __builtin_amdgcn_mfma_f32_16x16x32_bf16(pf0, v0, accO[nt], 0, 0, 0);
      accO[nt] = __builtin_amdgcn_mfma_f32_16x16x32_bf16(pf1, v1, accO[nt], 0, 0, 0);
    }
  }

  float inv[4];
#pragma unroll
  for (int r = 0; r < 4; r++) inv[r] = 1.f / l[r];
  __syncthreads();
#pragma unroll
  for (int nt = 0; nt < 4; nt++)
#pragma unroll
    for (int r = 0; r < 4; r++)
      Ps[wv * 16 + quad * 4 + r][nt * 16 + l16] = f2bf(accO[nt][r] * inv[r]);
  __syncthreads();
  int r = t >> 2, c0 = (t & 3) * 16;
  short8 o0 = *(const short8*)&Ps[r][c0];
  short8 o1 = *(const short8*)&Ps[r][c0 + 8];
  u16* dst = out + (size_t)(b * 1024 + qt * 64 + r) * 1024 + h * 64 + c0;
  *(short8*)dst = o0;
  *(short8*)(dst + 8) = o1;
}

// ---------------------------------------------------------------------------
// LayerNorm( xin + add ) * sc + bi  -> xout (f32) and xbf (bf16).
// ---------------------------------------------------------------------------
__global__ __launch_bounds__(256) void ln_kernel(
    const float* __restrict__ xin, const float* __restrict__ add,
    const float* __restrict__ sc, const float* __restrict__ bi,
    float* __restrict__ xout, u16* __restrict__ xbf)
{
  int row = blockIdx.x, t = threadIdx.x;
  float4 v = *(const float4*)(xin + (size_t)row * 1024 + t * 4);
  if (add) {
    float4 a = *(const float4*)(add + (size_t)row * 1024 + t * 4);
    v.x += a.x; v.y += a.y; v.z += a.z; v.w += a.w;
  }
  float s1 = v.x + v.y + v.z + v.w;
  float s2 = v.x * v.x + v.y * v.y + v.z * v.z + v.w * v.w;
#pragma unroll
  for (int off = 32; off > 0; off >>= 1) {
    s1 += __shfl_down(s1, off);
    s2 += __shfl_down(s2, off);
  }
  __shared__ float r1[4], r2[4];
  int lane = t & 63, wv = t >> 6;
  if (lane == 0) { r1[wv] = s1; r2[wv] = s2; }
  __syncthreads();
  float S1 = r1[0] + r1[1] + r1[2] + r1[3];
  float S2 = r2[0] + r2[1] + r2[2] + r2[3];
  float mn = S1 * (1.f / 1024.f);
  float var = S2 * (1.f / 1024.f) - mn * mn;
  float inv = rsqrtf(var + 1e-5f);
  float4 sv = *(const float4*)(sc + t * 4);
  float4 bv = *(const float4*)(bi + t * 4);
  float4 o;
  o.x = (v.x - mn) * inv * sv.x + bv.x;
  o.y = (v.y - mn) * inv * sv.y + bv.y;
  o.z = (v.z - mn) * inv * sv.z + bv.z;
  o.w = (v.w - mn) * inv * sv.w + bv.w;
  *(float4*)(xout + (size_t)row * 1024 + t * 4) = o;
  ushort4 ob; ob.x = f2bf(o.x); ob.y = f2bf(o.y); ob.z = f2bf(o.z); ob.w = f2bf(o.w);
  *(ushort4*)(xbf + (size_t)row * 1024 + t * 4) = ob;
}

// ---------------------------------------------------------------------------
// Final softmax: combine per-block partials (pass 1 fused into head GEMM),
// then one read+write pass over the logits.
// ---------------------------------------------------------------------------
__global__ __launch_bounds__(256) void softmax_final(
    float* __restrict__ out, const float2* __restrict__ partial, int pnb)
{
  int row = blockIdx.x, t = threadIdx.x;
  float m = -3.0e38f, s = 0.f;
  for (int j = t; j < pnb; j += 256) {
    float2 p = partial[(size_t)row * pnb + j];
    float mn = fmaxf(m, p.x);
    s = s * __expf(m - mn) + p.y * __expf(p.x - mn);
    m = mn;
  }
#pragma unroll
  for (int off = 32; off > 0; off >>= 1) {
    float m2 = __shfl_down(m, off), s2 = __shfl_down(s, off);
    float mn = fmaxf(m, m2);
    s = s * __expf(m - mn) + s2 * __expf(m2 - mn);
    m = mn;
  }
  __shared__ float rm[4], rs[4];
  int lane = t & 63, wv = t >> 6;
  if (lane == 0) { rm[wv] = m; rs[wv] = s; }
  __syncthreads();
  float M = rm[0], S = rs[0];
#pragma unroll
  for (int i = 1; i < 4; i++) {
    float mn = fmaxf(M, rm[i]);
    S = S * __expf(M - mn) + rs[i] * __expf(rm[i] - mn);
    M = mn;
  }
  float inv = 1.f / S;
  float4* p4 = (float4*)(out + (size_t)row * 32000);
  for (int j = t; j < 8000; j += 256) {
    float4 v = p4[j];
    v.x = __expf(v.x - M) * inv;
    v.y = __expf(v.y - M) * inv;
    v.z = __expf(v.z - M) * inv;
    v.w = __expf(v.w - M) * inv;
    p4[j] = v;
  }
}

// ---------------------------------------------------------------------------
// Launch
// ---------------------------------------------------------------------------
extern "C" void kernel_launch(void* const* d_in, const int* in_sizes, int n_in,
                              void* d_out, int out_size, void* d_ws, size_t ws_size,
                              hipStream_t stream)
{
  const int*   X       = (const int*)d_in[0];
  const float* tok_emb = (const float*)d_in[1];
  const float* pos_emb = (const float*)d_in[2];
  const float* qkv_w   = (const float*)d_in[3];
  const float* qkv_b   = (const float*)d_in[4];
  const float* out_w   = (const float*)d_in[5];
  const float* out_b   = (const float*)d_in[6];
  const float* ln1_s   = (const float*)d_in[7];
  const float* ln1_b   = (const float*)d_in[8];
  const float* ln2_s   = (const float*)d_in[9];
  const float* ln2_b   = (const float*)d_in[10];
  const float* ff1_w   = (const float*)d_in[11];
  const float* ff1_b   = (const float*)d_in[12];
  const float* ff2_w   = (const float*)d_in[13];
  const float* ff2_b   = (const float*)d_in[14];
  const float* lnf_s   = (const float*)d_in[15];
  const float* lnf_b   = (const float*)d_in[16];
  const float* head_w  = (const float*)d_in[17];
  const float* head_b  = (const float*)d_in[18];

  char* ws = (char*)d_ws;
  float* x      = (float*)ws;            ws += 2048ull * 1024 * 4;
  u16*   xbf    = (u16*)ws;              ws += 2048ull * 1024 * 2;
  u16*   qkvbuf = (u16*)ws;              ws += 2048ull * 3072 * 2;
  u16*   VTb    = (u16*)ws;              ws += 32ull * 64 * 1024 * 2;
  u16*   attnbf = (u16*)ws;              ws += 2048ull * 1024 * 2;
  float* tmp    = (float*)ws;            ws += 2048ull * 1024 * 4;
  u16*   hbf    = (u16*)ws;              ws += 2048ull * 4096 * 2;
  u16*   qkvT   = (u16*)ws;              ws += 3072ull * 1024 * 2;
  u16*   outT   = (u16*)ws;              ws += 1024ull * 1024 * 2;
  u16*   ff1T   = (u16*)ws;              ws += 4096ull * 1024 * 2;
  u16*   ff2T   = (u16*)ws;              ws += 1024ull * 4096 * 2;
  u16*   headT  = (u16*)ws;              ws += 32000ull * 1024 * 2;
  float2* smpart = (float2*)ws;          ws += 2048ull * 250 * 8;

  // all five weight transposes in one launch (block ranges inside)
  transpose_all<<<dim3(44288), 256, 0, stream>>>(
      qkv_w, qkvT, out_w, outT, ff1_w, ff1T, ff2_w, ff2T, head_w, headT);

  embed_kernel<<<2048, 256, 0, stream>>>(X, tok_emb, pos_emb, x, xbf);

  for (int l = 0; l < 6; l++) {
    // QKV GEMM with fused reshape: Q/K -> qkvbuf (bf16), V -> VTb (transposed)
    gemm_mfma<128, 2, 4, 4><<<dim3(3072 / 128, 2048 / 128), 256, 0, stream>>>(
        xbf, qkvT, qkv_b, qkvbuf, nullptr, VTb, 2048, 3072, 1024, 4);
    flash_attn<<<dim3(16, 16, 2), 256, 0, stream>>>(qkvbuf, VTb, attnbf);
    gemm_mfma<64, 4, 4, 2><<<dim3(1024 / 128, 2048 / 64), 256, 0, stream>>>(
        attnbf, outT, out_b, tmp, nullptr, nullptr, 2048, 1024, 1024, 0);
    ln_kernel<<<2048, 256, 0, stream>>>(x, tmp, ln1_s, ln1_b, x, xbf);
    gemm_mfma<128, 2, 4, 4><<<dim3(4096 / 128, 2048 / 128), 256, 0, stream>>>(
        xbf, ff1T, ff1_b, hbf, nullptr, nullptr, 2048, 4096, 1024, 1);
    gemm_mfma<64, 4, 4, 2><<<dim3(1024 / 128, 2048 / 64), 256, 0, stream>>>(
        hbf, ff2T, ff2_b, tmp, nullptr, nullptr, 2048, 1024, 4096, 0);
    ln_kernel<<<2048, 256, 0, stream>>>(x, tmp, ln2_s, ln2_b, x, xbf);
  }

  ln_kernel<<<2048, 256, 0, stream>>>(x, nullptr, lnf_s, lnf_b, x, xbf);
  // head GEMM: m97 structure (32 KiB LDS, 4000-wg grid) + fused softmax pass-1
  gemm_mfma<128, 2, 4, 4><<<dim3(32000 / 128, 2048 / 128), 256, 0, stream>>>(
      xbf, headT, head_b, (float*)d_out, smpart, nullptr, 2048, 32000, 1024, 2);
  softmax_final<<<2048, 256, 0, stream>>>((float*)d_out, smpart, 250);
}

// Round 9
// 2139.646 us; speedup vs baseline: 1.0173x; 1.0173x over previous
//
#include <hip/hip_runtime.h>
#include <math.h>

typedef unsigned short u16;
typedef short short8 __attribute__((ext_vector_type(8)));
typedef float floatx4 __attribute__((ext_vector_type(4)));

__device__ __forceinline__ u16 f2bf(float f) {
  unsigned int u = __float_as_uint(f);
  u += 0x7fffu + ((u >> 16) & 1u);
  return (u16)(u >> 16);
}

// async 16B global->LDS (DMA; LDS dest = wave-uniform base + lane*16)
__device__ __forceinline__ void gld_lds16(const void* g, void* l) {
  __builtin_amdgcn_global_load_lds(
      (__attribute__((address_space(1))) void*)(g),
      (__attribute__((address_space(3))) void*)(l), 16, 0, 0);
}

// ---------------------------------------------------------------------------
// Batched transpose + f32->bf16 convert for all 5 weights: W[K][N] -> Wt[N][K]
// ---------------------------------------------------------------------------
__global__ __launch_bounds__(256) void transpose_all(
    const float* __restrict__ W0, u16* __restrict__ T0,
    const float* __restrict__ W1, u16* __restrict__ T1,
    const float* __restrict__ W2, u16* __restrict__ T2,
    const float* __restrict__ W3, u16* __restrict__ T3,
    const float* __restrict__ W4, u16* __restrict__ T4)
{
  int bid = blockIdx.x;
  const float* W; u16* Wt; int K, N, lb;
  if (bid < 3072)       { W = W0; Wt = T0; K = 1024; N = 3072;  lb = bid;         }
  else if (bid < 4096)  { W = W1; Wt = T1; K = 1024; N = 1024;  lb = bid - 3072;  }
  else if (bid < 8192)  { W = W2; Wt = T2; K = 1024; N = 4096;  lb = bid - 4096;  }
  else if (bid < 12288) { W = W3; Wt = T3; K = 4096; N = 1024;  lb = bid - 8192;  }
  else                  { W = W4; Wt = T4; K = 1024; N = 32000; lb = bid - 12288; }
  int nbx = N >> 5;
  int bx = lb % nbx, by = lb / nbx;

  __shared__ float tile[32][33];
  int tx = threadIdx.x & 31, ty = threadIdx.x >> 5;
  int n0 = bx * 32, k0 = by * 32;
#pragma unroll
  for (int i = 0; i < 4; i++)
    tile[ty + i * 8][tx] = W[(size_t)(k0 + ty + i * 8) * N + n0 + tx];
  __syncthreads();
#pragma unroll
  for (int i = 0; i < 4; i++)
    Wt[(size_t)(n0 + ty + i * 8) * K + k0 + tx] = f2bf(tile[tx][ty + i * 8]);
}

// ---------------------------------------------------------------------------
// Embedding
// ---------------------------------------------------------------------------
__global__ __launch_bounds__(256) void embed_kernel(
    const int* __restrict__ X, const float* __restrict__ tok,
    const float* __restrict__ pos, float* __restrict__ x, u16* __restrict__ xbf)
{
  int bs = blockIdx.x, t = threadIdx.x;
  int id = X[bs];
  int s = bs & 1023;
  float4 tv = *(const float4*)(tok + (size_t)id * 1024 + t * 4);
  float4 pv = *(const float4*)(pos + (size_t)s * 1024 + t * 4);
  float4 o;
  o.x = tv.x + pv.x; o.y = tv.y + pv.y; o.z = tv.z + pv.z; o.w = tv.w + pv.w;
  *(float4*)(x + (size_t)bs * 1024 + t * 4) = o;
  ushort4 ob; ob.x = f2bf(o.x); ob.y = f2bf(o.y); ob.z = f2bf(o.z); ob.w = f2bf(o.w);
  *(ushort4*)(xbf + (size_t)bs * 1024 + t * 4) = ob;
}

// ---------------------------------------------------------------------------
// MFMA GEMM, m97-style: C[M][N] = A[M][K] @ Bt[N][K]^T + bias.
// SWZ=true (head only): column-major XCD chunking — each XCD owns a
// contiguous run of B-panel columns; B fetched once from HBM (R7 counters:
// without it, head FETCH=536MB and dur=285us pure fetch-bound; the 8-phase
// head WITH this swizzle measured FETCH=111MB).
// mode 0: C f32.  mode 1: C bf16 + exact GELU.
// mode 2: C f32 + per-(row, BN-col-block) softmax partials (max, sumexp).
// mode 4: QKV fused epilogue — Q/K bf16 into C (layout [s][3072]); V
//         scattered transposed into VTout[bh][64][1024] (8-B stores).
// ---------------------------------------------------------------------------
template<int BM, int WGC, int WTR, int WTC, bool SWZ>
__global__ __launch_bounds__(256) void gemm_mfma(
    const u16* __restrict__ A, const u16* __restrict__ Bt,
    const float* __restrict__ bias, void* __restrict__ Cout,
    float2* __restrict__ partial, u16* __restrict__ VTout,
    int M, int N, int K, int mode)
{
  constexpr int BN = WGC * WTC * 16;
  static_assert(BN == 128, "BN must be 128");
  __shared__ alignas(16) u16 As[BM * 64];
  __shared__ alignas(16) u16 Bs[128 * 64];

  const int t = threadIdx.x;
  const int wv = t >> 6, lane = t & 63;
  const int quad = lane >> 4, l16 = lane & 15;
  int bx, by;
  if (SWZ) {
    // column-major XCD chunking (bijective: nwg % 8 == 0 for the head grid)
    const int gx = (int)gridDim.x, gy = (int)gridDim.y;
    const int nwg = gx * gy;
    int hwid = (int)blockIdx.y * gx + (int)blockIdx.x;
    int tl = (hwid & 7) * (nwg >> 3) + (hwid >> 3);
    bx = tl / gy; by = tl % gy;
  } else {
    bx = (int)blockIdx.x; by = (int)blockIdx.y;
  }
  const int row0 = by * BM, col0 = bx * BN;
  const int wr = (wv / WGC) * (WTR * 16);
  const int wc = (wv % WGC) * (WTC * 16);
  const int wcid = wv % WGC;

  floatx4 acc[WTR][WTC];
#pragma unroll
  for (int i = 0; i < WTR; i++)
#pragma unroll
    for (int j = 0; j < WTC; j++) acc[i][j] = (floatx4){0.f, 0.f, 0.f, 0.f};

  // staging geometry: chunk = 8 rows x 64 cols (1 KB). lane -> (row, swizzled col)
  const int srow = lane >> 3;                 // row within chunk
  const int scol = ((lane & 7) ^ srow) * 8;   // XOR-swizzled column group
  const int swz = l16 & 7;                    // fragment-read swizzle key

  const u16* Abase = A + (size_t)row0 * K;
  const u16* Bbase = Bt + (size_t)col0 * K;
  constexpr int CA = BM / 32;  // A chunks per wave
  constexpr int CB = 4;        // B chunks per wave

  for (int k0 = 0; k0 < K; k0 += 64) {
#pragma unroll
    for (int i = 0; i < CA; i++) {
      int chunk = wv * CA + i;
      gld_lds16(Abase + (size_t)(chunk * 8 + srow) * K + k0 + scol, &As[chunk * 512]);
    }
#pragma unroll
    for (int i = 0; i < CB; i++) {
      int chunk = wv * CB + i;
      gld_lds16(Bbase + (size_t)(chunk * 8 + srow) * K + k0 + scol, &Bs[chunk * 512]);
    }
    __syncthreads();
#pragma unroll
    for (int ks = 0; ks < 64; ks += 32) {
      const int g = quad | (ks >> 3);          // global column group 0..7
      const int cofs = ((g ^ swz) * 8);        // swizzled LDS column
      short8 a[WTR], b[WTC];
#pragma unroll
      for (int i = 0; i < WTR; i++)
        a[i] = *(const short8*)&As[(wr + i * 16 + l16) * 64 + cofs];
#pragma unroll
      for (int j = 0; j < WTC; j++)
        b[j] = *(const short8*)&Bs[(wc + j * 16 + l16) * 64 + cofs];
#pragma unroll
      for (int i = 0; i < WTR; i++)
#pragma unroll
        for (int j = 0; j < WTC; j++)
          acc[i][j] = __builtin_amdgcn_mfma_f32_16x16x32_bf16(a[i], b[j], acc[i][j], 0, 0, 0);
    }
    __syncthreads();
  }

  // ---- epilogue ----
  float bvj[WTC];
#pragma unroll
  for (int j = 0; j < WTC; j++) bvj[j] = bias[col0 + wc + j * 16 + l16];

  if (mode == 2) {
    // f32 store + per-row (max, sumexp) partials over this block's BN cols.
    // LDS reuse of As (K-loop done, post-barrier): redm/reds BM*WGC floats.
    float* redm = (float*)As;
    float* reds = redm + BM * WGC;
#pragma unroll
    for (int i = 0; i < WTR; i++) {
      int rloc = wr + i * 16 + quad * 4;
      int rbase = row0 + rloc;
#pragma unroll
      for (int r = 0; r < 4; r++) {
        float vv[WTC];
        float mx = -3.0e38f;
#pragma unroll
        for (int j = 0; j < WTC; j++) {
          int c = col0 + wc + j * 16 + l16;
          float v = acc[i][j][r] + bvj[j];
          vv[j] = v;
          ((float*)Cout)[(size_t)(rbase + r) * N + c] = v;
          mx = fmaxf(mx, v);
        }
#pragma unroll
        for (int off = 1; off < 16; off <<= 1) mx = fmaxf(mx, __shfl_xor(mx, off, 64));
        float ss = 0.f;
#pragma unroll
        for (int j = 0; j < WTC; j++) ss += __expf(vv[j] - mx);
#pragma unroll
        for (int off = 1; off < 16; off <<= 1) ss += __shfl_xor(ss, off, 64);
        if (l16 == 0) {
          redm[(rloc + r) * WGC + wcid] = mx;
          reds[(rloc + r) * WGC + wcid] = ss;
        }
      }
    }
    __syncthreads();
    const int pnb = N / BN;
    for (int rr = t; rr < BM; rr += 256) {
      float M2 = redm[rr * WGC], S2 = reds[rr * WGC];
#pragma unroll
      for (int w = 1; w < WGC; w++) {
        float m2 = redm[rr * WGC + w], s2 = reds[rr * WGC + w];
        float mn = fmaxf(M2, m2);
        S2 = S2 * __expf(M2 - mn) + s2 * __expf(m2 - mn);
        M2 = mn;
      }
      partial[(size_t)(row0 + rr) * pnb + bx] = make_float2(M2, S2);
    }
  } else if (mode == 4) {
    // QKV: Q/K -> bf16 C in [s][3072] layout; V -> VTout[bh][64][1024]
#pragma unroll
    for (int i = 0; i < WTR; i++) {
      int rbase = row0 + wr + i * 16 + quad * 4;
#pragma unroll
      for (int j = 0; j < WTC; j++) {
        int c = col0 + wc + j * 16 + l16;
        int h = c / 192, within = c - h * 192;
        if (within < 128) {
#pragma unroll
          for (int r = 0; r < 4; r++)
            ((u16*)Cout)[(size_t)(rbase + r) * N + c] = f2bf(acc[i][j][r] + bvj[j]);
        } else {
          int d = within - 128;
          int bb = rbase >> 10, s0 = rbase & 1023;
          ushort4 ov;
          ov.x = f2bf(acc[i][j][0] + bvj[j]);
          ov.y = f2bf(acc[i][j][1] + bvj[j]);
          ov.z = f2bf(acc[i][j][2] + bvj[j]);
          ov.w = f2bf(acc[i][j][3] + bvj[j]);
          *(ushort4*)(VTout + ((size_t)(bb * 16 + h) * 64 + d) * 1024 + s0) = ov;
        }
      }
    }
  } else {
#pragma unroll
    for (int i = 0; i < WTR; i++) {
      int rbase = row0 + wr + i * 16 + quad * 4;
#pragma unroll
      for (int j = 0; j < WTC; j++) {
        int c = col0 + wc + j * 16 + l16;
#pragma unroll
        for (int r = 0; r < 4; r++) {
          float v = acc[i][j][r] + bvj[j];
          size_t idx = (size_t)(rbase + r) * N + c;
          if (mode == 0) {
            ((float*)Cout)[idx] = v;
          } else {  // mode 1: GELU bf16
            float gl = 0.5f * v * (1.f + erff(v * 0.70710678118f));
            ((u16*)Cout)[idx] = f2bf(gl);
          }
        }
      }
    }
  }
}

// ---------------------------------------------------------------------------
// Flash attention. Q/K read directly from qkvbuf bf16 [2048][3072]
// (per-lane 16-B segments); V^T from the VT buffer (QKV mode-4 epilogue).
// ---------------------------------------------------------------------------
__global__ __launch_bounds__(256) void flash_attn(
    const u16* __restrict__ qkv, const u16* __restrict__ VT,
    u16* __restrict__ out)
{
  __shared__ alignas(16) u16 Ps[64][72];
  int qt = (int)gridDim.x - 1 - (int)blockIdx.x;
  int h = blockIdx.y, b = blockIdx.z;
  int bh = b * 16 + h;
  int t = threadIdx.x;
  int wv = t >> 6, lane = t & 63, l16 = lane & 15, quad = lane >> 4;
  int qrow0 = qt * 64 + wv * 16;

  const u16* Qb = qkv + (size_t)b * 1024 * 3072 + h * 192;
  const u16* Kb = Qb + 64;
  const u16* Vb = VT + (size_t)bh * 64 * 1024;

  short8 qfrag[2];
  qfrag[0] = *(const short8*)(Qb + (size_t)(qrow0 + l16) * 3072 + quad * 8);
  qfrag[1] = *(const short8*)(Qb + (size_t)(qrow0 + l16) * 3072 + 32 + quad * 8);

  floatx4 accO[4];
#pragma unroll
  for (int i = 0; i < 4; i++) accO[i] = (floatx4){0.f, 0.f, 0.f, 0.f};
  float m[4], l[4];
#pragma unroll
  for (int r = 0; r < 4; r++) { m[r] = -3.0e38f; l[r] = 0.f; }

  for (int jt = 0; jt <= qt; jt++) {
    float sv[4][4];
    bool diag = (jt == qt);
#pragma unroll
    for (int nt = 0; nt < 4; nt++) {
      const u16* Kt = Kb + (size_t)(jt * 64 + nt * 16 + l16) * 3072;
      short8 b0 = *(const short8*)(Kt + quad * 8);
      short8 b1 = *(const short8*)(Kt + 32 + quad * 8);
      floatx4 acc = (floatx4){0.f, 0.f, 0.f, 0.f};
      acc = __builtin_amdgcn_mfma_f32_16x16x32_bf16(qfrag[0], b0, acc, 0, 0, 0);
      acc = __builtin_amdgcn_mfma_f32_16x16x32_bf16(qfrag[1], b1, acc, 0, 0, 0);
#pragma unroll
      for (int r = 0; r < 4; r++) {
        float v = acc[r] * 0.125f;
        if (diag) {
          int j = nt * 16 + l16;
          int q = wv * 16 + quad * 4 + r;
          if (j > q) v = -3.0e38f;
        }
        sv[nt][r] = v;
      }
    }
    float rm[4];
#pragma unroll
    for (int r = 0; r < 4; r++) {
      rm[r] = fmaxf(fmaxf(sv[0][r], sv[1][r]), fmaxf(sv[2][r], sv[3][r]));
#pragma unroll
      for (int off = 1; off < 16; off <<= 1)
        rm[r] = fmaxf(rm[r], __shfl_xor(rm[r], off, 64));
    }
    float al[4], rs[4];
    float p[4][4];
#pragma unroll
    for (int r = 0; r < 4; r++) {
      float mn = fmaxf(m[r], rm[r]);
      al[r] = __expf(m[r] - mn);
      m[r] = mn;
      rs[r] = 0.f;
    }
#pragma unroll
    for (int nt = 0; nt < 4; nt++)
#pragma unroll
      for (int r = 0; r < 4; r++) {
        float e = __expf(sv[nt][r] - m[r]);
        p[nt][r] = e;
        rs[r] += e;
      }
#pragma unroll
    for (int r = 0; r < 4; r++) {
#pragma unroll
      for (int off = 1; off < 16; off <<= 1)
        rs[r] += __shfl_xor(rs[r], off, 64);
      l[r] = l[r] * al[r] + rs[r];
    }
#pragma unroll
    for (int nt = 0; nt < 4; nt++)
#pragma unroll
      for (int r = 0; r < 4; r++) accO[nt][r] *= al[r];

    __syncthreads();
#pragma unroll
    for (int nt = 0; nt < 4; nt++)
#pragma unroll
      for (int r = 0; r < 4; r++)
        Ps[wv * 16 + quad * 4 + r][nt * 16 + l16] = f2bf(p[nt][r]);
    __syncthreads();

    short8 pf0 = *(const short8*)&Ps[wv * 16 + l16][quad * 8];
    short8 pf1 = *(const short8*)&Ps[wv * 16 + l16][32 + quad * 8];
#pragma unroll
    for (int nt = 0; nt < 4; nt++) {
      const u16* Vt = Vb + (size_t)(nt * 16 + l16) * 1024 + jt * 64;
      short8 v0 = *(const short8*)(Vt + quad * 8);
      short8 v1 = *(const short8*)(Vt + 32 + quad * 8);
      accO[nt] = __builtin_amdgcn_mfma_f32_16x16x32_bf16(pf0, v0, accO[nt], 0, 0, 0);
      accO[nt] = __builtin_amdgcn_mfma_f32_16x16x32_bf16(pf1, v1, accO[nt], 0, 0, 0);
    }
  }

  float inv[4];
#pragma unroll
  for (int r = 0; r < 4; r++) inv[r] = 1.f / l[r];
  __syncthreads();
#pragma unroll
  for (int nt = 0; nt < 4; nt++)
#pragma unroll
    for (int r = 0; r < 4; r++)
      Ps[wv * 16 + quad * 4 + r][nt * 16 + l16] = f2bf(accO[nt][r] * inv[r]);
  __syncthreads();
  int r = t >> 2, c0 = (t & 3) * 16;
  short8 o0 = *(const short8*)&Ps[r][c0];
  short8 o1 = *(const short8*)&Ps[r][c0 + 8];
  u16* dst = out + (size_t)(b * 1024 + qt * 64 + r) * 1024 + h * 64 + c0;
  *(short8*)dst = o0;
  *(short8*)(dst + 8) = o1;
}

// ---------------------------------------------------------------------------
// LayerNorm( xin + add ) * sc + bi  -> xout (f32) and xbf (bf16).
// ---------------------------------------------------------------------------
__global__ __launch_bounds__(256) void ln_kernel(
    const float* __restrict__ xin, const float* __restrict__ add,
    const float* __restrict__ sc, const float* __restrict__ bi,
    float* __restrict__ xout, u16* __restrict__ xbf)
{
  int row = blockIdx.x, t = threadIdx.x;
  float4 v = *(const float4*)(xin + (size_t)row * 1024 + t * 4);
  if (add) {
    float4 a = *(const float4*)(add + (size_t)row * 1024 + t * 4);
    v.x += a.x; v.y += a.y; v.z += a.z; v.w += a.w;
  }
  float s1 = v.x + v.y + v.z + v.w;
  float s2 = v.x * v.x + v.y * v.y + v.z * v.z + v.w * v.w;
#pragma unroll
  for (int off = 32; off > 0; off >>= 1) {
    s1 += __shfl_down(s1, off);
    s2 += __shfl_down(s2, off);
  }
  __shared__ float r1[4], r2[4];
  int lane = t & 63, wv = t >> 6;
  if (lane == 0) { r1[wv] = s1; r2[wv] = s2; }
  __syncthreads();
  float S1 = r1[0] + r1[1] + r1[2] + r1[3];
  float S2 = r2[0] + r2[1] + r2[2] + r2[3];
  float mn = S1 * (1.f / 1024.f);
  float var = S2 * (1.f / 1024.f) - mn * mn;
  float inv = rsqrtf(var + 1e-5f);
  float4 sv = *(const float4*)(sc + t * 4);
  float4 bv = *(const float4*)(bi + t * 4);
  float4 o;
  o.x = (v.x - mn) * inv * sv.x + bv.x;
  o.y = (v.y - mn) * inv * sv.y + bv.y;
  o.z = (v.z - mn) * inv * sv.z + bv.z;
  o.w = (v.w - mn) * inv * sv.w + bv.w;
  *(float4*)(xout + (size_t)row * 1024 + t * 4) = o;
  ushort4 ob; ob.x = f2bf(o.x); ob.y = f2bf(o.y); ob.z = f2bf(o.z); ob.w = f2bf(o.w);
  *(ushort4*)(xbf + (size_t)row * 1024 + t * 4) = ob;
}

// ---------------------------------------------------------------------------
// Final softmax: combine per-block partials (pass 1 fused into head GEMM),
// then one read+write pass over the logits.
// ---------------------------------------------------------------------------
__global__ __launch_bounds__(256) void softmax_final(
    float* __restrict__ out, const float2* __restrict__ partial, int pnb)
{
  int row = blockIdx.x, t = threadIdx.x;
  float m = -3.0e38f, s = 0.f;
  for (int j = t; j < pnb; j += 256) {
    float2 p = partial[(size_t)row * pnb + j];
    float mn = fmaxf(m, p.x);
    s = s * __expf(m - mn) + p.y * __expf(p.x - mn);
    m = mn;
  }
#pragma unroll
  for (int off = 32; off > 0; off >>= 1) {
    float m2 = __shfl_down(m, off), s2 = __shfl_down(s, off);
    float mn = fmaxf(m, m2);
    s = s * __expf(m - mn) + s2 * __expf(m2 - mn);
    m = mn;
  }
  __shared__ float rm[4], rs[4];
  int lane = t & 63, wv = t >> 6;
  if (lane == 0) { rm[wv] = m; rs[wv] = s; }
  __syncthreads();
  float M = rm[0], S = rs[0];
#pragma unroll
  for (int i = 1; i < 4; i++) {
    float mn = fmaxf(M, rm[i]);
    S = S * __expf(M - mn) + rs[i] * __expf(rm[i] - mn);
    M = mn;
  }
  float inv = 1.f / S;
  float4* p4 = (float4*)(out + (size_t)row * 32000);
  for (int j = t; j < 8000; j += 256) {
    float4 v = p4[j];
    v.x = __expf(v.x - M) * inv;
    v.y = __expf(v.y - M) * inv;
    v.z = __expf(v.z - M) * inv;
    v.w = __expf(v.w - M) * inv;
    p4[j] = v;
  }
}

// ---------------------------------------------------------------------------
// Launch
// ---------------------------------------------------------------------------
extern "C" void kernel_launch(void* const* d_in, const int* in_sizes, int n_in,
                              void* d_out, int out_size, void* d_ws, size_t ws_size,
                              hipStream_t stream)
{
  const int*   X       = (const int*)d_in[0];
  const float* tok_emb = (const float*)d_in[1];
  const float* pos_emb = (const float*)d_in[2];
  const float* qkv_w   = (const float*)d_in[3];
  const float* qkv_b   = (const float*)d_in[4];
  const float* out_w   = (const float*)d_in[5];
  const float* out_b   = (const float*)d_in[6];
  const float* ln1_s   = (const float*)d_in[7];
  const float* ln1_b   = (const float*)d_in[8];
  const float* ln2_s   = (const float*)d_in[9];
  const float* ln2_b   = (const float*)d_in[10];
  const float* ff1_w   = (const float*)d_in[11];
  const float* ff1_b   = (const float*)d_in[12];
  const float* ff2_w   = (const float*)d_in[13];
  const float* ff2_b   = (const float*)d_in[14];
  const float* lnf_s   = (const float*)d_in[15];
  const float* lnf_b   = (const float*)d_in[16];
  const float* head_w  = (const float*)d_in[17];
  const float* head_b  = (const float*)d_in[18];

  char* ws = (char*)d_ws;
  float* x      = (float*)ws;            ws += 2048ull * 1024 * 4;
  u16*   xbf    = (u16*)ws;              ws += 2048ull * 1024 * 2;
  u16*   qkvbuf = (u16*)ws;              ws += 2048ull * 3072 * 2;
  u16*   VTb    = (u16*)ws;              ws += 32ull * 64 * 1024 * 2;
  u16*   attnbf = (u16*)ws;              ws += 2048ull * 1024 * 2;
  float* tmp    = (float*)ws;            ws += 2048ull * 1024 * 4;
  u16*   hbf    = (u16*)ws;              ws += 2048ull * 4096 * 2;
  u16*   qkvT   = (u16*)ws;              ws += 3072ull * 1024 * 2;
  u16*   outT   = (u16*)ws;              ws += 1024ull * 1024 * 2;
  u16*   ff1T   = (u16*)ws;              ws += 4096ull * 1024 * 2;
  u16*   ff2T   = (u16*)ws;              ws += 1024ull * 4096 * 2;
  u16*   headT  = (u16*)ws;              ws += 32000ull * 1024 * 2;
  float2* smpart = (float2*)ws;          ws += 2048ull * 250 * 8;

  // all five weight transposes in one launch (block ranges inside)
  transpose_all<<<dim3(44288), 256, 0, stream>>>(
      qkv_w, qkvT, out_w, outT, ff1_w, ff1T, ff2_w, ff2T, head_w, headT);

  embed_kernel<<<2048, 256, 0, stream>>>(X, tok_emb, pos_emb, x, xbf);

  for (int l = 0; l < 6; l++) {
    // QKV GEMM with fused reshape: Q/K -> qkvbuf (bf16), V -> VTb (transposed)
    gemm_mfma<128, 2, 4, 4, false><<<dim3(3072 / 128, 2048 / 128), 256, 0, stream>>>(
        xbf, qkvT, qkv_b, qkvbuf, nullptr, VTb, 2048, 3072, 1024, 4);
    flash_attn<<<dim3(16, 16, 2), 256, 0, stream>>>(qkvbuf, VTb, attnbf);
    gemm_mfma<64, 4, 4, 2, false><<<dim3(1024 / 128, 2048 / 64), 256, 0, stream>>>(
        attnbf, outT, out_b, tmp, nullptr, nullptr, 2048, 1024, 1024, 0);
    ln_kernel<<<2048, 256, 0, stream>>>(x, tmp, ln1_s, ln1_b, x, xbf);
    gemm_mfma<128, 2, 4, 4, false><<<dim3(4096 / 128, 2048 / 128), 256, 0, stream>>>(
        xbf, ff1T, ff1_b, hbf, nullptr, nullptr, 2048, 4096, 1024, 1);
    gemm_mfma<64, 4, 4, 2, false><<<dim3(1024 / 128, 2048 / 64), 256, 0, stream>>>(
        hbf, ff2T, ff2_b, tmp, nullptr, nullptr, 2048, 1024, 4096, 0);
    ln_kernel<<<2048, 256, 0, stream>>>(x, tmp, ln2_s, ln2_b, x, xbf);
  }

  ln_kernel<<<2048, 256, 0, stream>>>(x, nullptr, lnf_s, lnf_b, x, xbf);
  // head GEMM: m97 structure + column-major XCD swizzle + fused softmax pass-1
  gemm_mfma<128, 2, 4, 4, true><<<dim3(32000 / 128, 2048 / 128), 256, 0, stream>>>(
      xbf, headT, head_b, (float*)d_out, smpart, nullptr, 2048, 32000, 1024, 2);
  softmax_final<<<2048, 256, 0, stream>>>((float*)d_out, smpart, 250);
}

// Round 10
// 1972.472 us; speedup vs baseline: 1.1036x; 1.0848x over previous
//
#include <hip/hip_runtime.h>
#include <math.h>

typedef unsigned short u16;
typedef short short8 __attribute__((ext_vector_type(8)));
typedef float floatx4 __attribute__((ext_vector_type(4)));

__device__ __forceinline__ u16 f2bf(float f) {
  unsigned int u = __float_as_uint(f);
  u += 0x7fffu + ((u >> 16) & 1u);
  return (u16)(u >> 16);
}

// async 16B global->LDS (DMA; LDS dest = wave-uniform base + lane*16)
__device__ __forceinline__ void gld_lds16(const void* g, void* l) {
  __builtin_amdgcn_global_load_lds(
      (__attribute__((address_space(1))) void*)(g),
      (__attribute__((address_space(3))) void*)(l), 16, 0, 0);
}

// ---------------------------------------------------------------------------
// Batched transpose + f32->bf16 convert for all 5 weights: W[K][N] -> Wt[N][K]
// ---------------------------------------------------------------------------
__global__ __launch_bounds__(256) void transpose_all(
    const float* __restrict__ W0, u16* __restrict__ T0,
    const float* __restrict__ W1, u16* __restrict__ T1,
    const float* __restrict__ W2, u16* __restrict__ T2,
    const float* __restrict__ W3, u16* __restrict__ T3,
    const float* __restrict__ W4, u16* __restrict__ T4)
{
  int bid = blockIdx.x;
  const float* W; u16* Wt; int K, N, lb;
  if (bid < 3072)       { W = W0; Wt = T0; K = 1024; N = 3072;  lb = bid;         }
  else if (bid < 4096)  { W = W1; Wt = T1; K = 1024; N = 1024;  lb = bid - 3072;  }
  else if (bid < 8192)  { W = W2; Wt = T2; K = 1024; N = 4096;  lb = bid - 4096;  }
  else if (bid < 12288) { W = W3; Wt = T3; K = 4096; N = 1024;  lb = bid - 8192;  }
  else                  { W = W4; Wt = T4; K = 1024; N = 32000; lb = bid - 12288; }
  int nbx = N >> 5;
  int bx = lb % nbx, by = lb / nbx;

  __shared__ float tile[32][33];
  int tx = threadIdx.x & 31, ty = threadIdx.x >> 5;
  int n0 = bx * 32, k0 = by * 32;
#pragma unroll
  for (int i = 0; i < 4; i++)
    tile[ty + i * 8][tx] = W[(size_t)(k0 + ty + i * 8) * N + n0 + tx];
  __syncthreads();
#pragma unroll
  for (int i = 0; i < 4; i++)
    Wt[(size_t)(n0 + ty + i * 8) * K + k0 + tx] = f2bf(tile[tx][ty + i * 8]);
}

// ---------------------------------------------------------------------------
// Embedding
// ---------------------------------------------------------------------------
__global__ __launch_bounds__(256) void embed_kernel(
    const int* __restrict__ X, const float* __restrict__ tok,
    const float* __restrict__ pos, float* __restrict__ x, u16* __restrict__ xbf)
{
  int bs = blockIdx.x, t = threadIdx.x;
  int id = X[bs];
  int s = bs & 1023;
  float4 tv = *(const float4*)(tok + (size_t)id * 1024 + t * 4);
  float4 pv = *(const float4*)(pos + (size_t)s * 1024 + t * 4);
  float4 o;
  o.x = tv.x + pv.x; o.y = tv.y + pv.y; o.z = tv.z + pv.z; o.w = tv.w + pv.w;
  *(float4*)(x + (size_t)bs * 1024 + t * 4) = o;
  ushort4 ob; ob.x = f2bf(o.x); ob.y = f2bf(o.y); ob.z = f2bf(o.z); ob.w = f2bf(o.w);
  *(ushort4*)(xbf + (size_t)bs * 1024 + t * 4) = ob;
}

// ---------------------------------------------------------------------------
// MFMA GEMM, m97-style: C[M][N] = A[M][K] @ Bt[N][K]^T + bias.
// BN = WGC*WTC*16 ∈ {64, 128}. BN=64 (proj/ff2): doubles grid to 512 wg ->
// 2 blocks/CU (R9 theory: 256-wg grids ran 1 blk/CU = 1 wave/SIMD, fully
// exposing the per-K-iter vmcnt(0) load latency; ff2 has 64 such stalls).
// mode 0: C f32.  mode 1: C bf16 + exact GELU.
// mode 4: QKV fused epilogue — Q/K bf16 into C (layout [s][3072]); V
//         scattered transposed into VTout[bh][64][1024] (8-B stores).
// ---------------------------------------------------------------------------
template<int BM, int WGC, int WTR, int WTC>
__global__ __launch_bounds__(256) void gemm_mfma(
    const u16* __restrict__ A, const u16* __restrict__ Bt,
    const float* __restrict__ bias, void* __restrict__ Cout,
    u16* __restrict__ VTout,
    int M, int N, int K, int mode)
{
  constexpr int BN = WGC * WTC * 16;
  static_assert(BN == 128 || BN == 64, "BN must be 64 or 128");
  __shared__ alignas(16) u16 As[BM * 64];
  __shared__ alignas(16) u16 Bs[BN * 64];

  const int t = threadIdx.x;
  const int wv = t >> 6, lane = t & 63;
  const int quad = lane >> 4, l16 = lane & 15;
  const int bx = blockIdx.x, by = blockIdx.y;
  const int row0 = by * BM, col0 = bx * BN;
  const int wr = (wv / WGC) * (WTR * 16);
  const int wc = (wv % WGC) * (WTC * 16);

  floatx4 acc[WTR][WTC];
#pragma unroll
  for (int i = 0; i < WTR; i++)
#pragma unroll
    for (int j = 0; j < WTC; j++) acc[i][j] = (floatx4){0.f, 0.f, 0.f, 0.f};

  // staging geometry: chunk = 8 rows x 64 cols (1 KB). lane -> (row, swizzled col)
  const int srow = lane >> 3;                 // row within chunk
  const int scol = ((lane & 7) ^ srow) * 8;   // XOR-swizzled column group
  const int swz = l16 & 7;                    // fragment-read swizzle key

  const u16* Abase = A + (size_t)row0 * K;
  const u16* Bbase = Bt + (size_t)col0 * K;
  constexpr int CA = BM / 32;  // A chunks per wave
  constexpr int CB = BN / 32;  // B chunks per wave

  for (int k0 = 0; k0 < K; k0 += 64) {
#pragma unroll
    for (int i = 0; i < CA; i++) {
      int chunk = wv * CA + i;
      gld_lds16(Abase + (size_t)(chunk * 8 + srow) * K + k0 + scol, &As[chunk * 512]);
    }
#pragma unroll
    for (int i = 0; i < CB; i++) {
      int chunk = wv * CB + i;
      gld_lds16(Bbase + (size_t)(chunk * 8 + srow) * K + k0 + scol, &Bs[chunk * 512]);
    }
    __syncthreads();
#pragma unroll
    for (int ks = 0; ks < 64; ks += 32) {
      const int g = quad | (ks >> 3);          // global column group 0..7
      const int cofs = ((g ^ swz) * 8);        // swizzled LDS column
      short8 a[WTR], b[WTC];
#pragma unroll
      for (int i = 0; i < WTR; i++)
        a[i] = *(const short8*)&As[(wr + i * 16 + l16) * 64 + cofs];
#pragma unroll
      for (int j = 0; j < WTC; j++)
        b[j] = *(const short8*)&Bs[(wc + j * 16 + l16) * 64 + cofs];
#pragma unroll
      for (int i = 0; i < WTR; i++)
#pragma unroll
        for (int j = 0; j < WTC; j++)
          acc[i][j] = __builtin_amdgcn_mfma_f32_16x16x32_bf16(a[i], b[j], acc[i][j], 0, 0, 0);
    }
    __syncthreads();
  }

  // ---- epilogue ----
  float bvj[WTC];
#pragma unroll
  for (int j = 0; j < WTC; j++) bvj[j] = bias[col0 + wc + j * 16 + l16];

  if (mode == 4) {
    // QKV: Q/K -> bf16 C in [s][3072] layout; V -> VTout[bh][64][1024]
#pragma unroll
    for (int i = 0; i < WTR; i++) {
      int rbase = row0 + wr + i * 16 + quad * 4;
#pragma unroll
      for (int j = 0; j < WTC; j++) {
        int c = col0 + wc + j * 16 + l16;
        int h = c / 192, within = c - h * 192;
        if (within < 128) {
#pragma unroll
          for (int r = 0; r < 4; r++)
            ((u16*)Cout)[(size_t)(rbase + r) * N + c] = f2bf(acc[i][j][r] + bvj[j]);
        } else {
          int d = within - 128;
          int bb = rbase >> 10, s0 = rbase & 1023;
          ushort4 ov;
          ov.x = f2bf(acc[i][j][0] + bvj[j]);
          ov.y = f2bf(acc[i][j][1] + bvj[j]);
          ov.z = f2bf(acc[i][j][2] + bvj[j]);
          ov.w = f2bf(acc[i][j][3] + bvj[j]);
          *(ushort4*)(VTout + ((size_t)(bb * 16 + h) * 64 + d) * 1024 + s0) = ov;
        }
      }
    }
  } else {
#pragma unroll
    for (int i = 0; i < WTR; i++) {
      int rbase = row0 + wr + i * 16 + quad * 4;
#pragma unroll
      for (int j = 0; j < WTC; j++) {
        int c = col0 + wc + j * 16 + l16;
#pragma unroll
        for (int r = 0; r < 4; r++) {
          float v = acc[i][j][r] + bvj[j];
          size_t idx = (size_t)(rbase + r) * N + c;
          if (mode == 0) {
            ((float*)Cout)[idx] = v;
          } else {  // mode 1: GELU bf16
            float gl = 0.5f * v * (1.f + erff(v * 0.70710678118f));
            ((u16*)Cout)[idx] = f2bf(gl);
          }
        }
      }
    }
  }
}

// ---------------------------------------------------------------------------
// 256x256 8-phase GEMM for the head (grid 125x8 = 1000 wg, 512 thr).
// R5-verified: 196.9us, FETCH 113MB, passed refcheck. Relaxed barriers
// (pre-MFMA hw barrier removed; WAR closed by END-of-phase barrier, RAW by
// end-of-tile vmcnt(6)+barrier). Column-major XCD swizzle keeps B read-once.
// mode 2: C f32 + bias + per-(row, 256-col block) softmax partials.
// ---------------------------------------------------------------------------
__global__ __launch_bounds__(512) void gemm_256_8ph(
    const u16* __restrict__ A, const u16* __restrict__ Bt,
    const float* __restrict__ bias, float* __restrict__ Cout,
    float2* __restrict__ partial, int M, int N, int K, int mode)
{
  __shared__ alignas(16) u16 As[2][256 * 64];
  __shared__ alignas(16) u16 Bs[2][256 * 64];

  const int t = threadIdx.x;
  const int wv = t >> 6, lane = t & 63;
  const int quad = lane >> 4, l16 = lane & 15;
  const int wm = wv >> 2, wn = wv & 3;

  int bx, by;
  {
    const int gx = (int)gridDim.x, gy = (int)gridDim.y;
    const int nwg = gx * gy;
    int hwid = (int)blockIdx.y * gx + (int)blockIdx.x;
    if ((nwg & 7) == 0) {
      int tl = (hwid & 7) * (nwg >> 3) + (hwid >> 3);  // XCD-contiguous
      bx = tl / gy; by = tl % gy;                      // column-major tiles
    } else { bx = (int)blockIdx.x; by = (int)blockIdx.y; }
  }
  const int row0 = by * 256, col0 = bx * 256;

  const int srow = lane >> 3, lcol = lane & 7;
  const int scol = (lcol ^ srow) * 8;  // XOR-swizzled source column group
  const int swz = l16 & 7;

  const u16* Abase = A + (size_t)row0 * K;
  const u16* Bbase = Bt + (size_t)col0 * K;
  const int NT = K >> 6;

  floatx4 acc[8][4];
#pragma unroll
  for (int i = 0; i < 8; i++)
#pragma unroll
    for (int j = 0; j < 4; j++) acc[i][j] = (floatx4){0.f, 0.f, 0.f, 0.f};

  // stage A-half mh of K-tile T into buffer b (2 x gld_lds per wave)
  auto stageA = [&](int b, int T, int mh) {
    const int kk = T * 64;
#pragma unroll
    for (int i = 0; i < 2; i++) {
      int ch = wv * 2 + i;                                  // 0..15
      int chunk = ((ch >> 3) * 16) + mh * 8 + (ch & 7);     // 8-row chunk id
      gld_lds16(Abase + (size_t)(chunk * 8 + srow) * K + kk + scol,
                &As[b][chunk * 512]);
    }
  };
  // stage B-half nh of K-tile T into buffer b
  auto stageB = [&](int b, int T, int nh) {
    const int kk = T * 64;
#pragma unroll
    for (int i = 0; i < 2; i++) {
      int ch = wv * 2 + i;
      int chunk = ((ch >> 2) * 8) + nh * 4 + (ch & 3);
      gld_lds16(Bbase + (size_t)(chunk * 8 + srow) * K + kk + scol,
                &Bs[b][chunk * 512]);
    }
  };

  // prologue: Ah0(0) Bh0(0) Ah1(0) Bh1(0) Ah0(1) Bh0(1) Ah1(1); vmcnt(6)
  stageA(0, 0, 0); stageB(0, 0, 0); stageA(0, 0, 1); stageB(0, 0, 1);
  if (NT > 1) {
    stageA(1, 1, 0); stageB(1, 1, 0); stageA(1, 1, 1);
    asm volatile("s_waitcnt vmcnt(6)" ::: "memory");
  } else {
    asm volatile("s_waitcnt vmcnt(0)" ::: "memory");
  }
  __builtin_amdgcn_s_barrier();

  short8 af[4][2], bf0[2][2], bf1[2][2];
  for (int T = 0; T < NT; T++) {
    const int b = T & 1, bn = b ^ 1;

    // ---- phase 1: quadrant (0,0) ----
#pragma unroll
    for (int m = 0; m < 4; m++)
#pragma unroll
      for (int ks = 0; ks < 2; ks++) {
        int row = wm * 128 + m * 16 + l16;
        int g = quad + ks * 4;
        af[m][ks] = *(const short8*)&As[b][row * 64 + ((g ^ swz) * 8)];
      }
#pragma unroll
    for (int n = 0; n < 2; n++)
#pragma unroll
      for (int ks = 0; ks < 2; ks++) {
        int row = wn * 64 + n * 16 + l16;
        int g = quad + ks * 4;
        bf0[n][ks] = *(const short8*)&Bs[b][row * 64 + ((g ^ swz) * 8)];
      }
    if (T + 1 < NT) stageB(bn, T + 1, 1);
    asm volatile("" ::: "memory");   // compiler fence: pin stage/read vs MFMA
    __builtin_amdgcn_s_setprio(1);
#pragma unroll
    for (int m = 0; m < 4; m++)
#pragma unroll
      for (int n = 0; n < 2; n++)
#pragma unroll
        for (int ks = 0; ks < 2; ks++)
          acc[m][n] = __builtin_amdgcn_mfma_f32_16x16x32_bf16(af[m][ks], bf0[n][ks], acc[m][n], 0, 0, 0);
    __builtin_amdgcn_s_setprio(0);
    __builtin_amdgcn_s_barrier();

    // ---- phase 2: quadrant (0,1) ----
#pragma unroll
    for (int n = 0; n < 2; n++)
#pragma unroll
      for (int ks = 0; ks < 2; ks++) {
        int row = wn * 64 + 32 + n * 16 + l16;
        int g = quad + ks * 4;
        bf1[n][ks] = *(const short8*)&Bs[b][row * 64 + ((g ^ swz) * 8)];
      }
    if (T + 2 < NT) stageA(b, T + 2, 0);
    asm volatile("" ::: "memory");
    __builtin_amdgcn_s_setprio(1);
#pragma unroll
    for (int m = 0; m < 4; m++)
#pragma unroll
      for (int n = 0; n < 2; n++)
#pragma unroll
        for (int ks = 0; ks < 2; ks++)
          acc[m][2 + n] = __builtin_amdgcn_mfma_f32_16x16x32_bf16(af[m][ks], bf1[n][ks], acc[m][2 + n], 0, 0, 0);
    __builtin_amdgcn_s_setprio(0);
    __builtin_amdgcn_s_barrier();

    // ---- phase 3: quadrant (1,0) ----
#pragma unroll
    for (int m = 0; m < 4; m++)
#pragma unroll
      for (int ks = 0; ks < 2; ks++) {
        int row = wm * 128 + 64 + m * 16 + l16;
        int g = quad + ks * 4;
        af[m][ks] = *(const short8*)&As[b][row * 64 + ((g ^ swz) * 8)];
      }
    if (T + 2 < NT) stageB(b, T + 2, 0);
    asm volatile("" ::: "memory");
    __builtin_amdgcn_s_setprio(1);
#pragma unroll
    for (int m = 0; m < 4; m++)
#pragma unroll
      for (int n = 0; n < 2; n++)
#pragma unroll
        for (int ks = 0; ks < 2; ks++)
          acc[4 + m][n] = __builtin_amdgcn_mfma_f32_16x16x32_bf16(af[m][ks], bf0[n][ks], acc[4 + m][n], 0, 0, 0);
    __builtin_amdgcn_s_setprio(0);
    __builtin_amdgcn_s_barrier();

    // ---- phase 4: quadrant (1,1) ----
    if (T + 2 < NT) stageA(b, T + 2, 1);
    asm volatile("" ::: "memory");
    __builtin_amdgcn_s_setprio(1);
#pragma unroll
    for (int m = 0; m < 4; m++)
#pragma unroll
      for (int n = 0; n < 2; n++)
#pragma unroll
        for (int ks = 0; ks < 2; ks++)
          acc[4 + m][2 + n] = __builtin_amdgcn_mfma_f32_16x16x32_bf16(af[m][ks], bf1[n][ks], acc[4 + m][2 + n], 0, 0, 0);
    __builtin_amdgcn_s_setprio(0);
    if (T + 2 < NT) asm volatile("s_waitcnt vmcnt(6)" ::: "memory");
    else            asm volatile("s_waitcnt vmcnt(0)" ::: "memory");
    __builtin_amdgcn_s_barrier();
  }

  // ---- epilogue ----
  float* redm = (float*)&As[0][0];
  float* reds = redm + 256 * 4;

  float bvj[4];
#pragma unroll
  for (int j = 0; j < 4; j++)
    bvj[j] = bias[col0 + wn * 64 + (j >> 1) * 32 + (j & 1) * 16 + l16];

#pragma unroll
  for (int i = 0; i < 8; i++) {
    int rloc = wm * 128 + (i >> 2) * 64 + (i & 3) * 16 + quad * 4;
    int rbase = row0 + rloc;
    if (mode == 2) {
#pragma unroll
      for (int r = 0; r < 4; r++) {
        float vv[4];
        float mx = -3.0e38f;
#pragma unroll
        for (int j = 0; j < 4; j++) {
          int c = col0 + wn * 64 + (j >> 1) * 32 + (j & 1) * 16 + l16;
          float v = acc[i][j][r] + bvj[j];
          vv[j] = v;
          Cout[(size_t)(rbase + r) * N + c] = v;
          mx = fmaxf(mx, v);
        }
#pragma unroll
        for (int off = 1; off < 16; off <<= 1) mx = fmaxf(mx, __shfl_xor(mx, off, 64));
        float ss = 0.f;
#pragma unroll
        for (int j = 0; j < 4; j++) ss += __expf(vv[j] - mx);
#pragma unroll
        for (int off = 1; off < 16; off <<= 1) ss += __shfl_xor(ss, off, 64);
        if (l16 == 0) {
          redm[(rloc + r) * 4 + wn] = mx;
          reds[(rloc + r) * 4 + wn] = ss;
        }
      }
    } else {
#pragma unroll
      for (int j = 0; j < 4; j++) {
        int c = col0 + wn * 64 + (j >> 1) * 32 + (j & 1) * 16 + l16;
#pragma unroll
        for (int r = 0; r < 4; r++)
          Cout[(size_t)(rbase + r) * N + c] = acc[i][j][r] + bvj[j];
      }
    }
  }
  if (mode == 2) {
    __syncthreads();
    const int pnb = N >> 8;  // N / 256
    if (t < 256) {
      float M2 = redm[t * 4], S2 = reds[t * 4];
#pragma unroll
      for (int w = 1; w < 4; w++) {
        float m2 = redm[t * 4 + w], s2 = reds[t * 4 + w];
        float mn = fmaxf(M2, m2);
        S2 = S2 * __expf(M2 - mn) + s2 * __expf(m2 - mn);
        M2 = mn;
      }
      partial[(size_t)(row0 + t) * pnb + bx] = make_float2(M2, S2);
    }
  }
}

// ---------------------------------------------------------------------------
// Flash attention. Q/K read directly from qkvbuf bf16 [2048][3072]
// (per-lane 16-B segments); V^T from the VT buffer (QKV mode-4 epilogue).
// ---------------------------------------------------------------------------
__global__ __launch_bounds__(256) void flash_attn(
    const u16* __restrict__ qkv, const u16* __restrict__ VT,
    u16* __restrict__ out)
{
  __shared__ alignas(16) u16 Ps[64][72];
  int qt = (int)gridDim.x - 1 - (int)blockIdx.x;
  int h = blockIdx.y, b = blockIdx.z;
  int bh = b * 16 + h;
  int t = threadIdx.x;
  int wv = t >> 6, lane = t & 63, l16 = lane & 15, quad = lane >> 4;
  int qrow0 = qt * 64 + wv * 16;

  const u16* Qb = qkv + (size_t)b * 1024 * 3072 + h * 192;
  const u16* Kb = Qb + 64;
  const u16* Vb = VT + (size_t)bh * 64 * 1024;

  short8 qfrag[2];
  qfrag[0] = *(const short8*)(Qb + (size_t)(qrow0 + l16) * 3072 + quad * 8);
  qfrag[1] = *(const short8*)(Qb + (size_t)(qrow0 + l16) * 3072 + 32 + quad * 8);

  floatx4 accO[4];
#pragma unroll
  for (int i = 0; i < 4; i++) accO[i] = (floatx4){0.f, 0.f, 0.f, 0.f};
  float m[4], l[4];
#pragma unroll
  for (int r = 0; r < 4; r++) { m[r] = -3.0e38f; l[r] = 0.f; }

  for (int jt = 0; jt <= qt; jt++) {
    float sv[4][4];
    bool diag = (jt == qt);
#pragma unroll
    for (int nt = 0; nt < 4; nt++) {
      const u16* Kt = Kb + (size_t)(jt * 64 + nt * 16 + l16) * 3072;
      short8 b0 = *(const short8*)(Kt + quad * 8);
      short8 b1 = *(const short8*)(Kt + 32 + quad * 8);
      floatx4 acc = (floatx4){0.f, 0.f, 0.f, 0.f};
      acc = __builtin_amdgcn_mfma_f32_16x16x32_bf16(qfrag[0], b0, acc, 0, 0, 0);
      acc = __builtin_amdgcn_mfma_f32_16x16x32_bf16(qfrag[1], b1, acc, 0, 0, 0);
#pragma unroll
      for (int r = 0; r < 4; r++) {
        float v = acc[r] * 0.125f;
        if (diag) {
          int j = nt * 16 + l16;
          int q = wv * 16 + quad * 4 + r;
          if (j > q) v = -3.0e38f;
        }
        sv[nt][r] = v;
      }
    }
    float rm[4];
#pragma unroll
    for (int r = 0; r < 4; r++) {
      rm[r] = fmaxf(fmaxf(sv[0][r], sv[1][r]), fmaxf(sv[2][r], sv[3][r]));
#pragma unroll
      for (int off = 1; off < 16; off <<= 1)
        rm[r] = fmaxf(rm[r], __shfl_xor(rm[r], off, 64));
    }
    float al[4], rs[4];
    float p[4][4];
#pragma unroll
    for (int r = 0; r < 4; r++) {
      float mn = fmaxf(m[r], rm[r]);
      al[r] = __expf(m[r] - mn);
      m[r] = mn;
      rs[r] = 0.f;
    }
#pragma unroll
    for (int nt = 0; nt < 4; nt++)
#pragma unroll
      for (int r = 0; r < 4; r++) {
        float e = __expf(sv[nt][r] - m[r]);
        p[nt][r] = e;
        rs[r] += e;
      }
#pragma unroll
    for (int r = 0; r < 4; r++) {
#pragma unroll
      for (int off = 1; off < 16; off <<= 1)
        rs[r] += __shfl_xor(rs[r], off, 64);
      l[r] = l[r] * al[r] + rs[r];
    }
#pragma unroll
    for (int nt = 0; nt < 4; nt++)
#pragma unroll
      for (int r = 0; r < 4; r++) accO[nt][r] *= al[r];

    __syncthreads();
#pragma unroll
    for (int nt = 0; nt < 4; nt++)
#pragma unroll
      for (int r = 0; r < 4; r++)
        Ps[wv * 16 + quad * 4 + r][nt * 16 + l16] = f2bf(p[nt][r]);
    __syncthreads();

    short8 pf0 = *(const short8*)&Ps[wv * 16 + l16][quad * 8];
    short8 pf1 = *(const short8*)&Ps[wv * 16 + l16][32 + quad * 8];
#pragma unroll
    for (int nt = 0; nt < 4; nt++) {
      const u16* Vt = Vb + (size_t)(nt * 16 + l16) * 1024 + jt * 64;
      short8 v0 = *(const short8*)(Vt + quad * 8);
      short8 v1 = *(const short8*)(Vt + 32 + quad * 8);
      accO[nt] = __builtin_amdgcn_mfma_f32_16x16x32_bf16(pf0, v0, accO[nt], 0, 0, 0);
      accO[nt] = __builtin_amdgcn_mfma_f32_16x16x32_bf16(pf1, v1, accO[nt], 0, 0, 0);
    }
  }

  float inv[4];
#pragma unroll
  for (int r = 0; r < 4; r++) inv[r] = 1.f / l[r];
  __syncthreads();
#pragma unroll
  for (int nt = 0; nt < 4; nt++)
#pragma unroll
    for (int r = 0; r < 4; r++)
      Ps[wv * 16 + quad * 4 + r][nt * 16 + l16] = f2bf(accO[nt][r] * inv[r]);
  __syncthreads();
  int r = t >> 2, c0 = (t & 3) * 16;
  short8 o0 = *(const short8*)&Ps[r][c0];
  short8 o1 = *(const short8*)&Ps[r][c0 + 8];
  u16* dst = out + (size_t)(b * 1024 + qt * 64 + r) * 1024 + h * 64 + c0;
  *(short8*)dst = o0;
  *(short8*)(dst + 8) = o1;
}

// ---------------------------------------------------------------------------
// LayerNorm( xin + add ) * sc + bi  -> xout (f32) and xbf (bf16).
// ---------------------------------------------------------------------------
__global__ __launch_bounds__(256) void ln_kernel(
    const float* __restrict__ xin, const float* __restrict__ add,
    const float* __restrict__ sc, const float* __restrict__ bi,
    float* __restrict__ xout, u16* __restrict__ xbf)
{
  int row = blockIdx.x, t = threadIdx.x;
  float4 v = *(const float4*)(xin + (size_t)row * 1024 + t * 4);
  if (add) {
    float4 a = *(const float4*)(add + (size_t)row * 1024 + t * 4);
    v.x += a.x; v.y += a.y; v.z += a.z; v.w += a.w;
  }
  float s1 = v.x + v.y + v.z + v.w;
  float s2 = v.x * v.x + v.y * v.y + v.z * v.z + v.w * v.w;
#pragma unroll
  for (int off = 32; off > 0; off >>= 1) {
    s1 += __shfl_down(s1, off);
    s2 += __shfl_down(s2, off);
  }
  __shared__ float r1[4], r2[4];
  int lane = t & 63, wv = t >> 6;
  if (lane == 0) { r1[wv] = s1; r2[wv] = s2; }
  __syncthreads();
  float S1 = r1[0] + r1[1] + r1[2] + r1[3];
  float S2 = r2[0] + r2[1] + r2[2] + r2[3];
  float mn = S1 * (1.f / 1024.f);
  float var = S2 * (1.f / 1024.f) - mn * mn;
  float inv = rsqrtf(var + 1e-5f);
  float4 sv = *(const float4*)(sc + t * 4);
  float4 bv = *(const float4*)(bi + t * 4);
  float4 o;
  o.x = (v.x - mn) * inv * sv.x + bv.x;
  o.y = (v.y - mn) * inv * sv.y + bv.y;
  o.z = (v.z - mn) * inv * sv.z + bv.z;
  o.w = (v.w - mn) * inv * sv.w + bv.w;
  *(float4*)(xout + (size_t)row * 1024 + t * 4) = o;
  ushort4 ob; ob.x = f2bf(o.x); ob.y = f2bf(o.y); ob.z = f2bf(o.z); ob.w = f2bf(o.w);
  *(ushort4*)(xbf + (size_t)row * 1024 + t * 4) = ob;
}

// ---------------------------------------------------------------------------
// Final softmax: combine per-block partials (pass 1 fused into head GEMM),
// then one read+write pass over the logits.
// ---------------------------------------------------------------------------
__global__ __launch_bounds__(256) void softmax_final(
    float* __restrict__ out, const float2* __restrict__ partial, int pnb)
{
  int row = blockIdx.x, t = threadIdx.x;
  float m = -3.0e38f, s = 0.f;
  for (int j = t; j < pnb; j += 256) {
    float2 p = partial[(size_t)row * pnb + j];
    float mn = fmaxf(m, p.x);
    s = s * __expf(m - mn) + p.y * __expf(p.x - mn);
    m = mn;
  }
#pragma unroll
  for (int off = 32; off > 0; off >>= 1) {
    float m2 = __shfl_down(m, off), s2 = __shfl_down(s, off);
    float mn = fmaxf(m, m2);
    s = s * __expf(m - mn) + s2 * __expf(m2 - mn);
    m = mn;
  }
  __shared__ float rm[4], rs[4];
  int lane = t & 63, wv = t >> 6;
  if (lane == 0) { rm[wv] = m; rs[wv] = s; }
  __syncthreads();
  float M = rm[0], S = rs[0];
#pragma unroll
  for (int i = 1; i < 4; i++) {
    float mn = fmaxf(M, rm[i]);
    S = S * __expf(M - mn) + rs[i] * __expf(rm[i] - mn);
    M = mn;
  }
  float inv = 1.f / S;
  float4* p4 = (float4*)(out + (size_t)row * 32000);
  for (int j = t; j < 8000; j += 256) {
    float4 v = p4[j];
    v.x = __expf(v.x - M) * inv;
    v.y = __expf(v.y - M) * inv;
    v.z = __expf(v.z - M) * inv;
    v.w = __expf(v.w - M) * inv;
    p4[j] = v;
  }
}

// ---------------------------------------------------------------------------
// Launch
// ---------------------------------------------------------------------------
extern "C" void kernel_launch(void* const* d_in, const int* in_sizes, int n_in,
                              void* d_out, int out_size, void* d_ws, size_t ws_size,
                              hipStream_t stream)
{
  const int*   X       = (const int*)d_in[0];
  const float* tok_emb = (const float*)d_in[1];
  const float* pos_emb = (const float*)d_in[2];
  const float* qkv_w   = (const float*)d_in[3];
  const float* qkv_b   = (const float*)d_in[4];
  const float* out_w   = (const float*)d_in[5];
  const float* out_b   = (const float*)d_in[6];
  const float* ln1_s   = (const float*)d_in[7];
  const float* ln1_b   = (const float*)d_in[8];
  const float* ln2_s   = (const float*)d_in[9];
  const float* ln2_b   = (const float*)d_in[10];
  const float* ff1_w   = (const float*)d_in[11];
  const float* ff1_b   = (const float*)d_in[12];
  const float* ff2_w   = (const float*)d_in[13];
  const float* ff2_b   = (const float*)d_in[14];
  const float* lnf_s   = (const float*)d_in[15];
  const float* lnf_b   = (const float*)d_in[16];
  const float* head_w  = (const float*)d_in[17];
  const float* head_b  = (const float*)d_in[18];

  char* ws = (char*)d_ws;
  float* x      = (float*)ws;            ws += 2048ull * 1024 * 4;
  u16*   xbf    = (u16*)ws;              ws += 2048ull * 1024 * 2;
  u16*   qkvbuf = (u16*)ws;              ws += 2048ull * 3072 * 2;
  u16*   VTb    = (u16*)ws;              ws += 32ull * 64 * 1024 * 2;
  u16*   attnbf = (u16*)ws;              ws += 2048ull * 1024 * 2;
  float* tmp    = (float*)ws;            ws += 2048ull * 1024 * 4;
  u16*   hbf    = (u16*)ws;              ws += 2048ull * 4096 * 2;
  u16*   qkvT   = (u16*)ws;              ws += 3072ull * 1024 * 2;
  u16*   outT   = (u16*)ws;              ws += 1024ull * 1024 * 2;
  u16*   ff1T   = (u16*)ws;              ws += 4096ull * 1024 * 2;
  u16*   ff2T   = (u16*)ws;              ws += 1024ull * 4096 * 2;
  u16*   headT  = (u16*)ws;              ws += 32000ull * 1024 * 2;
  float2* smpart = (float2*)ws;          ws += 2048ull * 250 * 8;

  // all five weight transposes in one launch (block ranges inside)
  transpose_all<<<dim3(44288), 256, 0, stream>>>(
      qkv_w, qkvT, out_w, outT, ff1_w, ff1T, ff2_w, ff2T, head_w, headT);

  embed_kernel<<<2048, 256, 0, stream>>>(X, tok_emb, pos_emb, x, xbf);

  for (int l = 0; l < 6; l++) {
    // QKV GEMM with fused reshape: Q/K -> qkvbuf (bf16), V -> VTb (transposed)
    gemm_mfma<128, 2, 4, 4><<<dim3(3072 / 128, 2048 / 128), 256, 0, stream>>>(
        xbf, qkvT, qkv_b, qkvbuf, VTb, 2048, 3072, 1024, 4);
    flash_attn<<<dim3(16, 16, 2), 256, 0, stream>>>(qkvbuf, VTb, attnbf);
    // proj: BN=64 tiles -> 512 wg = 2 blocks/CU (was 256 wg = 1/CU)
    gemm_mfma<64, 4, 4, 1><<<dim3(1024 / 64, 2048 / 64), 256, 0, stream>>>(
        attnbf, outT, out_b, tmp, nullptr, 2048, 1024, 1024, 0);
    ln_kernel<<<2048, 256, 0, stream>>>(x, tmp, ln1_s, ln1_b, x, xbf);
    gemm_mfma<128, 2, 4, 4><<<dim3(4096 / 128, 2048 / 128), 256, 0, stream>>>(
        xbf, ff1T, ff1_b, hbf, nullptr, 2048, 4096, 1024, 1);
    // ff2: BN=64 tiles -> 512 wg = 2 blocks/CU (K=4096: 64 latency-stalls/block)
    gemm_mfma<64, 4, 4, 1><<<dim3(1024 / 64, 2048 / 64), 256, 0, stream>>>(
        hbf, ff2T, ff2_b, tmp, nullptr, 2048, 1024, 4096, 0);
    ln_kernel<<<2048, 256, 0, stream>>>(x, tmp, ln2_s, ln2_b, x, xbf);
  }

  ln_kernel<<<2048, 256, 0, stream>>>(x, nullptr, lnf_s, lnf_b, x, xbf);
  // head GEMM: 8-phase 256^2 (R5-verified 196.9us) + fused softmax pass-1
  gemm_256_8ph<<<dim3(32000 / 256, 2048 / 256), 512, 0, stream>>>(
      xbf, headT, head_b, (float*)d_out, smpart, 2048, 32000, 1024, 2);
  softmax_final<<<2048, 256, 0, stream>>>((float*)d_out, smpart, 125);
}

// Round 12
// 1926.423 us; speedup vs baseline: 1.1299x; 1.0239x over previous
//
#include <hip/hip_runtime.h>
#include <math.h>

typedef unsigned short u16;
typedef short short8 __attribute__((ext_vector_type(8)));
typedef float floatx4 __attribute__((ext_vector_type(4)));

__device__ __forceinline__ u16 f2bf(float f) {
  unsigned int u = __float_as_uint(f);
  u += 0x7fffu + ((u >> 16) & 1u);
  return (u16)(u >> 16);
}

// async 16B global->LDS (DMA; LDS dest = wave-uniform base + lane*16)
__device__ __forceinline__ void gld_lds16(const void* g, void* l) {
  __builtin_amdgcn_global_load_lds(
      (__attribute__((address_space(1))) void*)(g),
      (__attribute__((address_space(3))) void*)(l), 16, 0, 0);
}

// ---------------------------------------------------------------------------
// Batched transpose + f32->bf16 convert for all 5 weights: W[K][N] -> Wt[N][K]
// ---------------------------------------------------------------------------
__global__ __launch_bounds__(256) void transpose_all(
    const float* __restrict__ W0, u16* __restrict__ T0,
    const float* __restrict__ W1, u16* __restrict__ T1,
    const float* __restrict__ W2, u16* __restrict__ T2,
    const float* __restrict__ W3, u16* __restrict__ T3,
    const float* __restrict__ W4, u16* __restrict__ T4)
{
  int bid = blockIdx.x;
  const float* W; u16* Wt; int K, N, lb;
  if (bid < 3072)       { W = W0; Wt = T0; K = 1024; N = 3072;  lb = bid;         }
  else if (bid < 4096)  { W = W1; Wt = T1; K = 1024; N = 1024;  lb = bid - 3072;  }
  else if (bid < 8192)  { W = W2; Wt = T2; K = 1024; N = 4096;  lb = bid - 4096;  }
  else if (bid < 12288) { W = W3; Wt = T3; K = 4096; N = 1024;  lb = bid - 8192;  }
  else                  { W = W4; Wt = T4; K = 1024; N = 32000; lb = bid - 12288; }
  int nbx = N >> 5;
  int bx = lb % nbx, by = lb / nbx;

  __shared__ float tile[32][33];
  int tx = threadIdx.x & 31, ty = threadIdx.x >> 5;
  int n0 = bx * 32, k0 = by * 32;
#pragma unroll
  for (int i = 0; i < 4; i++)
    tile[ty + i * 8][tx] = W[(size_t)(k0 + ty + i * 8) * N + n0 + tx];
  __syncthreads();
#pragma unroll
  for (int i = 0; i < 4; i++)
    Wt[(size_t)(n0 + ty + i * 8) * K + k0 + tx] = f2bf(tile[tx][ty + i * 8]);
}

// ---------------------------------------------------------------------------
// Embedding
// ---------------------------------------------------------------------------
__global__ __launch_bounds__(256) void embed_kernel(
    const int* __restrict__ X, const float* __restrict__ tok,
    const float* __restrict__ pos, float* __restrict__ x, u16* __restrict__ xbf)
{
  int bs = blockIdx.x, t = threadIdx.x;
  int id = X[bs];
  int s = bs & 1023;
  float4 tv = *(const float4*)(tok + (size_t)id * 1024 + t * 4);
  float4 pv = *(const float4*)(pos + (size_t)s * 1024 + t * 4);
  float4 o;
  o.x = tv.x + pv.x; o.y = tv.y + pv.y; o.z = tv.z + pv.z; o.w = tv.w + pv.w;
  *(float4*)(x + (size_t)bs * 1024 + t * 4) = o;
  ushort4 ob; ob.x = f2bf(o.x); ob.y = f2bf(o.y); ob.z = f2bf(o.z); ob.w = f2bf(o.w);
  *(ushort4*)(xbf + (size_t)bs * 1024 + t * 4) = ob;
}

// ---------------------------------------------------------------------------
// MFMA GEMM, 2-phase double-buffered (T3-minimum recipe): stage(T+1) is
// issued BEFORE compute(T), so global->LDS DMA flies under the MFMAs; one
// vmcnt(0)+barrier per K-tile (was: stage fully serialized after compute —
// R10 theory: at 1.5-2 blocks/CU the loop GEMMs expose full load latency
// every K-iter; ff2 pays 64 such stalls at K=4096).
// Hazards (re-audited R11): reads of buf[cur^1] completed before the
// end-of-(T-1) barrier (WAR-safe early stage); buf[cur]'s DMA drained by
// that barrier's preceding vmcnt(0) (RAW-safe).
// BN = WGC*WTC*16 ∈ {64, 128}. LDS: 2x(BM+BN)x64x2B = 64KB/32KB.
// mode 0: C f32.  mode 1: C bf16 + exact GELU.
// mode 4: QKV fused epilogue — Q/K bf16 into C (layout [s][3072]); V
//         scattered transposed into VTout[bh][64][1024] (8-B stores).
// ---------------------------------------------------------------------------
template<int BM, int WGC, int WTR, int WTC>
__global__ __launch_bounds__(256) void gemm_mfma(
    const u16* __restrict__ A, const u16* __restrict__ Bt,
    const float* __restrict__ bias, void* __restrict__ Cout,
    u16* __restrict__ VTout,
    int M, int N, int K, int mode)
{
  constexpr int BN = WGC * WTC * 16;
  static_assert(BN == 128 || BN == 64, "BN must be 64 or 128");
  __shared__ alignas(16) u16 As[2][BM * 64];
  __shared__ alignas(16) u16 Bs[2][BN * 64];

  const int t = threadIdx.x;
  const int wv = t >> 6, lane = t & 63;
  const int quad = lane >> 4, l16 = lane & 15;
  const int bx = blockIdx.x, by = blockIdx.y;
  const int row0 = by * BM, col0 = bx * BN;
  const int wr = (wv / WGC) * (WTR * 16);
  const int wc = (wv % WGC) * (WTC * 16);

  floatx4 acc[WTR][WTC];
#pragma unroll
  for (int i = 0; i < WTR; i++)
#pragma unroll
    for (int j = 0; j < WTC; j++) acc[i][j] = (floatx4){0.f, 0.f, 0.f, 0.f};

  // staging geometry: chunk = 8 rows x 64 cols (1 KB). lane -> (row, swizzled col)
  const int srow = lane >> 3;                 // row within chunk
  const int scol = ((lane & 7) ^ srow) * 8;   // XOR-swizzled column group
  const int swz = l16 & 7;                    // fragment-read swizzle key

  const u16* Abase = A + (size_t)row0 * K;
  const u16* Bbase = Bt + (size_t)col0 * K;
  constexpr int CA = BM / 32;  // A chunks per wave
  constexpr int CB = BN / 32;  // B chunks per wave
  const int NT = K >> 6;

  auto stage = [&](int b, int T) {
    const int kk = T * 64;
#pragma unroll
    for (int i = 0; i < CA; i++) {
      int chunk = wv * CA + i;
      gld_lds16(Abase + (size_t)(chunk * 8 + srow) * K + kk + scol, &As[b][chunk * 512]);
    }
#pragma unroll
    for (int i = 0; i < CB; i++) {
      int chunk = wv * CB + i;
      gld_lds16(Bbase + (size_t)(chunk * 8 + srow) * K + kk + scol, &Bs[b][chunk * 512]);
    }
  };

  stage(0, 0);
  asm volatile("s_waitcnt vmcnt(0)" ::: "memory");
  __builtin_amdgcn_s_barrier();

  for (int T = 0; T < NT; T++) {
    const int cur = T & 1;
    if (T + 1 < NT) stage(cur ^ 1, T + 1);  // issue-early: DMA under compute
    asm volatile("" ::: "memory");          // pin DMA issue above ds_reads
#pragma unroll
    for (int ks = 0; ks < 64; ks += 32) {
      const int g = quad | (ks >> 3);          // global column group 0..7
      const int cofs = ((g ^ swz) * 8);        // swizzled LDS column
      short8 a[WTR], b[WTC];
#pragma unroll
      for (int i = 0; i < WTR; i++)
        a[i] = *(const short8*)&As[cur][(wr + i * 16 + l16) * 64 + cofs];
#pragma unroll
      for (int j = 0; j < WTC; j++)
        b[j] = *(const short8*)&Bs[cur][(wc + j * 16 + l16) * 64 + cofs];
#pragma unroll
      for (int i = 0; i < WTR; i++)
#pragma unroll
        for (int j = 0; j < WTC; j++)
          acc[i][j] = __builtin_amdgcn_mfma_f32_16x16x32_bf16(a[i], b[j], acc[i][j], 0, 0, 0);
    }
    asm volatile("s_waitcnt vmcnt(0)" ::: "memory");  // prefetch landed (hidden)
    __builtin_amdgcn_s_barrier();
  }

  // ---- epilogue ----
  float bvj[WTC];
#pragma unroll
  for (int j = 0; j < WTC; j++) bvj[j] = bias[col0 + wc + j * 16 + l16];

  if (mode == 4) {
    // QKV: Q/K -> bf16 C in [s][3072] layout; V -> VTout[bh][64][1024]
#pragma unroll
    for (int i = 0; i < WTR; i++) {
      int rbase = row0 + wr + i * 16 + quad * 4;
#pragma unroll
      for (int j = 0; j < WTC; j++) {
        int c = col0 + wc + j * 16 + l16;
        int h = c / 192, within = c - h * 192;
        if (within < 128) {
#pragma unroll
          for (int r = 0; r < 4; r++)
            ((u16*)Cout)[(size_t)(rbase + r) * N + c] = f2bf(acc[i][j][r] + bvj[j]);
        } else {
          int d = within - 128;
          int bb = rbase >> 10, s0 = rbase & 1023;
          ushort4 ov;
          ov.x = f2bf(acc[i][j][0] + bvj[j]);
          ov.y = f2bf(acc[i][j][1] + bvj[j]);
          ov.z = f2bf(acc[i][j][2] + bvj[j]);
          ov.w = f2bf(acc[i][j][3] + bvj[j]);
          *(ushort4*)(VTout + ((size_t)(bb * 16 + h) * 64 + d) * 1024 + s0) = ov;
        }
      }
    }
  } else {
#pragma unroll
    for (int i = 0; i < WTR; i++) {
      int rbase = row0 + wr + i * 16 + quad * 4;
#pragma unroll
      for (int j = 0; j < WTC; j++) {
        int c = col0 + wc + j * 16 + l16;
#pragma unroll
        for (int r = 0; r < 4; r++) {
          float v = acc[i][j][r] + bvj[j];
          size_t idx = (size_t)(rbase + r) * N + c;
          if (mode == 0) {
            ((float*)Cout)[idx] = v;
          } else {  // mode 1: GELU bf16
            float gl = 0.5f * v * (1.f + erff(v * 0.70710678118f));
            ((u16*)Cout)[idx] = f2bf(gl);
          }
        }
      }
    }
  }
}

// ---------------------------------------------------------------------------
// 256x256 8-phase GEMM for the head (grid 125x8 = 1000 wg, 512 thr).
// R5-verified: 196.9us, FETCH 113MB, passed refcheck. Relaxed barriers
// (pre-MFMA hw barrier removed; WAR closed by END-of-phase barrier, RAW by
// end-of-tile vmcnt(6)+barrier). Column-major XCD swizzle keeps B read-once.
// mode 2: C f32 + bias + per-(row, 256-col block) softmax partials.
// ---------------------------------------------------------------------------
__global__ __launch_bounds__(512) void gemm_256_8ph(
    const u16* __restrict__ A, const u16* __restrict__ Bt,
    const float* __restrict__ bias, float* __restrict__ Cout,
    float2* __restrict__ partial, int M, int N, int K, int mode)
{
  __shared__ alignas(16) u16 As[2][256 * 64];
  __shared__ alignas(16) u16 Bs[2][256 * 64];

  const int t = threadIdx.x;
  const int wv = t >> 6, lane = t & 63;
  const int quad = lane >> 4, l16 = lane & 15;
  const int wm = wv >> 2, wn = wv & 3;

  int bx, by;
  {
    const int gx = (int)gridDim.x, gy = (int)gridDim.y;
    const int nwg = gx * gy;
    int hwid = (int)blockIdx.y * gx + (int)blockIdx.x;
    if ((nwg & 7) == 0) {
      int tl = (hwid & 7) * (nwg >> 3) + (hwid >> 3);  // XCD-contiguous
      bx = tl / gy; by = tl % gy;                      // column-major tiles
    } else { bx = (int)blockIdx.x; by = (int)blockIdx.y; }
  }
  const int row0 = by * 256, col0 = bx * 256;

  const int srow = lane >> 3, lcol = lane & 7;
  const int scol = (lcol ^ srow) * 8;  // XOR-swizzled source column group
  const int swz = l16 & 7;

  const u16* Abase = A + (size_t)row0 * K;
  const u16* Bbase = Bt + (size_t)col0 * K;
  const int NT = K >> 6;

  floatx4 acc[8][4];
#pragma unroll
  for (int i = 0; i < 8; i++)
#pragma unroll
    for (int j = 0; j < 4; j++) acc[i][j] = (floatx4){0.f, 0.f, 0.f, 0.f};

  // stage A-half mh of K-tile T into buffer b (2 x gld_lds per wave)
  auto stageA = [&](int b, int T, int mh) {
    const int kk = T * 64;
#pragma unroll
    for (int i = 0; i < 2; i++) {
      int ch = wv * 2 + i;                                  // 0..15
      int chunk = ((ch >> 3) * 16) + mh * 8 + (ch & 7);     // 8-row chunk id
      gld_lds16(Abase + (size_t)(chunk * 8 + srow) * K + kk + scol,
                &As[b][chunk * 512]);
    }
  };
  // stage B-half nh of K-tile T into buffer b
  auto stageB = [&](int b, int T, int nh) {
    const int kk = T * 64;
#pragma unroll
    for (int i = 0; i < 2; i++) {
      int ch = wv * 2 + i;
      int chunk = ((ch >> 2) * 8) + nh * 4 + (ch & 3);
      gld_lds16(Bbase + (size_t)(chunk * 8 + srow) * K + kk + scol,
                &Bs[b][chunk * 512]);
    }
  };

  // prologue: Ah0(0) Bh0(0) Ah1(0) Bh1(0) Ah0(1) Bh0(1) Ah1(1); vmcnt(6)
  stageA(0, 0, 0); stageB(0, 0, 0); stageA(0, 0, 1); stageB(0, 0, 1);
  if (NT > 1) {
    stageA(1, 1, 0); stageB(1, 1, 0); stageA(1, 1, 1);
    asm volatile("s_waitcnt vmcnt(6)" ::: "memory");
  } else {
    asm volatile("s_waitcnt vmcnt(0)" ::: "memory");
  }
  __builtin_amdgcn_s_barrier();

  short8 af[4][2], bf0[2][2], bf1[2][2];
  for (int T = 0; T < NT; T++) {
    const int b = T & 1, bn = b ^ 1;

    // ---- phase 1: quadrant (0,0) ----
#pragma unroll
    for (int m = 0; m < 4; m++)
#pragma unroll
      for (int ks = 0; ks < 2; ks++) {
        int row = wm * 128 + m * 16 + l16;
        int g = quad + ks * 4;
        af[m][ks] = *(const short8*)&As[b][row * 64 + ((g ^ swz) * 8)];
      }
#pragma unroll
    for (int n = 0; n < 2; n++)
#pragma unroll
      for (int ks = 0; ks < 2; ks++) {
        int row = wn * 64 + n * 16 + l16;
        int g = quad + ks * 4;
        bf0[n][ks] = *(const short8*)&Bs[b][row * 64 + ((g ^ swz) * 8)];
      }
    if (T + 1 < NT) stageB(bn, T + 1, 1);
    asm volatile("" ::: "memory");   // compiler fence: pin stage/read vs MFMA
    __builtin_amdgcn_s_setprio(1);
#pragma unroll
    for (int m = 0; m < 4; m++)
#pragma unroll
      for (int n = 0; n < 2; n++)
#pragma unroll
        for (int ks = 0; ks < 2; ks++)
          acc[m][n] = __builtin_amdgcn_mfma_f32_16x16x32_bf16(af[m][ks], bf0[n][ks], acc[m][n], 0, 0, 0);
    __builtin_amdgcn_s_setprio(0);
    __builtin_amdgcn_s_barrier();

    // ---- phase 2: quadrant (0,1) ----
#pragma unroll
    for (int n = 0; n < 2; n++)
#pragma unroll
      for (int ks = 0; ks < 2; ks++) {
        int row = wn * 64 + 32 + n * 16 + l16;
        int g = quad + ks * 4;
        bf1[n][ks] = *(const short8*)&Bs[b][row * 64 + ((g ^ swz) * 8)];
      }
    if (T + 2 < NT) stageA(b, T + 2, 0);
    asm volatile("" ::: "memory");
    __builtin_amdgcn_s_setprio(1);
#pragma unroll
    for (int m = 0; m < 4; m++)
#pragma unroll
      for (int n = 0; n < 2; n++)
#pragma unroll
        for (int ks = 0; ks < 2; ks++)
          acc[m][2 + n] = __builtin_amdgcn_mfma_f32_16x16x32_bf16(af[m][ks], bf1[n][ks], acc[m][2 + n], 0, 0, 0);
    __builtin_amdgcn_s_setprio(0);
    __builtin_amdgcn_s_barrier();

    // ---- phase 3: quadrant (1,0) ----
#pragma unroll
    for (int m = 0; m < 4; m++)
#pragma unroll
      for (int ks = 0; ks < 2; ks++) {
        int row = wm * 128 + 64 + m * 16 + l16;
        int g = quad + ks * 4;
        af[m][ks] = *(const short8*)&As[b][row * 64 + ((g ^ swz) * 8)];
      }
    if (T + 2 < NT) stageB(b, T + 2, 0);
    asm volatile("" ::: "memory");
    __builtin_amdgcn_s_setprio(1);
#pragma unroll
    for (int m = 0; m < 4; m++)
#pragma unroll
      for (int n = 0; n < 2; n++)
#pragma unroll
        for (int ks = 0; ks < 2; ks++)
          acc[4 + m][n] = __builtin_amdgcn_mfma_f32_16x16x32_bf16(af[m][ks], bf0[n][ks], acc[4 + m][n], 0, 0, 0);
    __builtin_amdgcn_s_setprio(0);
    __builtin_amdgcn_s_barrier();

    // ---- phase 4: quadrant (1,1) ----
    if (T + 2 < NT) stageA(b, T + 2, 1);
    asm volatile("" ::: "memory");
    __builtin_amdgcn_s_setprio(1);
#pragma unroll
    for (int m = 0; m < 4; m++)
#pragma unroll
      for (int n = 0; n < 2; n++)
#pragma unroll
        for (int ks = 0; ks < 2; ks++)
          acc[4 + m][2 + n] = __builtin_amdgcn_mfma_f32_16x16x32_bf16(af[m][ks], bf1[n][ks], acc[4 + m][2 + n], 0, 0, 0);
    __builtin_amdgcn_s_setprio(0);
    if (T + 2 < NT) asm volatile("s_waitcnt vmcnt(6)" ::: "memory");
    else            asm volatile("s_waitcnt vmcnt(0)" ::: "memory");
    __builtin_amdgcn_s_barrier();
  }

  // ---- epilogue ----
  float* redm = (float*)&As[0][0];
  float* reds = redm + 256 * 4;

  float bvj[4];
#pragma unroll
  for (int j = 0; j < 4; j++)
    bvj[j] = bias[col0 + wn * 64 + (j >> 1) * 32 + (j & 1) * 16 + l16];

#pragma unroll
  for (int i = 0; i < 8; i++) {
    int rloc = wm * 128 + (i >> 2) * 64 + (i & 3) * 16 + quad * 4;
    int rbase = row0 + rloc;
    if (mode == 2) {
#pragma unroll
      for (int r = 0; r < 4; r++) {
        float vv[4];
        float mx = -3.0e38f;
#pragma unroll
        for (int j = 0; j < 4; j++) {
          int c = col0 + wn * 64 + (j >> 1) * 32 + (j & 1) * 16 + l16;
          float v = acc[i][j][r] + bvj[j];
          vv[j] = v;
          Cout[(size_t)(rbase + r) * N + c] = v;
          mx = fmaxf(mx, v);
        }
#pragma unroll
        for (int off = 1; off < 16; off <<= 1) mx = fmaxf(mx, __shfl_xor(mx, off, 64));
        float ss = 0.f;
#pragma unroll
        for (int j = 0; j < 4; j++) ss += __expf(vv[j] - mx);
#pragma unroll
        for (int off = 1; off < 16; off <<= 1) ss += __shfl_xor(ss, off, 64);
        if (l16 == 0) {
          redm[(rloc + r) * 4 + wn] = mx;
          reds[(rloc + r) * 4 + wn] = ss;
        }
      }
    } else {
#pragma unroll
      for (int j = 0; j < 4; j++) {
        int c = col0 + wn * 64 + (j >> 1) * 32 + (j & 1) * 16 + l16;
#pragma unroll
        for (int r = 0; r < 4; r++)
          Cout[(size_t)(rbase + r) * N + c] = acc[i][j][r] + bvj[j];
      }
    }
  }
  if (mode == 2) {
    __syncthreads();
    const int pnb = N >> 8;  // N / 256
    if (t < 256) {
      float M2 = redm[t * 4], S2 = reds[t * 4];
#pragma unroll
      for (int w = 1; w < 4; w++) {
        float m2 = redm[t * 4 + w], s2 = reds[t * 4 + w];
        float mn = fmaxf(M2, m2);
        S2 = S2 * __expf(M2 - mn) + s2 * __expf(m2 - mn);
        M2 = mn;
      }
      partial[(size_t)(row0 + t) * pnb + bx] = make_float2(M2, S2);
    }
  }
}

// ---------------------------------------------------------------------------
// Flash attention. Q/K read directly from qkvbuf bf16 [2048][3072]
// (per-lane 16-B segments); V^T from the VT buffer (QKV mode-4 epilogue).
// ---------------------------------------------------------------------------
__global__ __launch_bounds__(256) void flash_attn(
    const u16* __restrict__ qkv, const u16* __restrict__ VT,
    u16* __restrict__ out)
{
  __shared__ alignas(16) u16 Ps[64][72];
  int qt = (int)gridDim.x - 1 - (int)blockIdx.x;
  int h = blockIdx.y, b = blockIdx.z;
  int bh = b * 16 + h;
  int t = threadIdx.x;
  int wv = t >> 6, lane = t & 63, l16 = lane & 15, quad = lane >> 4;
  int qrow0 = qt * 64 + wv * 16;

  const u16* Qb = qkv + (size_t)b * 1024 * 3072 + h * 192;
  const u16* Kb = Qb + 64;
  const u16* Vb = VT + (size_t)bh * 64 * 1024;

  short8 qfrag[2];
  qfrag[0] = *(const short8*)(Qb + (size_t)(qrow0 + l16) * 3072 + quad * 8);
  qfrag[1] = *(const short8*)(Qb + (size_t)(qrow0 + l16) * 3072 + 32 + quad * 8);

  floatx4 accO[4];
#pragma unroll
  for (int i = 0; i < 4; i++) accO[i] = (floatx4){0.f, 0.f, 0.f, 0.f};
  float m[4], l[4];
#pragma unroll
  for (int r = 0; r < 4; r++) { m[r] = -3.0e38f; l[r] = 0.f; }

  for (int jt = 0; jt <= qt; jt++) {
    float sv[4][4];
    bool diag = (jt == qt);
#pragma unroll
    for (int nt = 0; nt < 4; nt++) {
      const u16* Kt = Kb + (size_t)(jt * 64 + nt * 16 + l16) * 3072;
      short8 b0 = *(const short8*)(Kt + quad * 8);
      short8 b1 = *(const short8*)(Kt + 32 + quad * 8);
      floatx4 acc = (floatx4){0.f, 0.f, 0.f, 0.f};
      acc = __builtin_amdgcn_mfma_f32_16x16x32_bf16(qfrag[0], b0, acc, 0, 0, 0);
      acc = __builtin_amdgcn_mfma_f32_16x16x32_bf16(qfrag[1], b1, acc, 0, 0, 0);
#pragma unroll
      for (int r = 0; r < 4; r++) {
        float v = acc[r] * 0.125f;
        if (diag) {
          int j = nt * 16 + l16;
          int q = wv * 16 + quad * 4 + r;
          if (j > q) v = -3.0e38f;
        }
        sv[nt][r] = v;
      }
    }
    float rm[4];
#pragma unroll
    for (int r = 0; r < 4; r++) {
      rm[r] = fmaxf(fmaxf(sv[0][r], sv[1][r]), fmaxf(sv[2][r], sv[3][r]));
#pragma unroll
      for (int off = 1; off < 16; off <<= 1)
        rm[r] = fmaxf(rm[r], __shfl_xor(rm[r], off, 64));
    }
    float al[4], rs[4];
    float p[4][4];
#pragma unroll
    for (int r = 0; r < 4; r++) {
      float mn = fmaxf(m[r], rm[r]);
      al[r] = __expf(m[r] - mn);
      m[r] = mn;
      rs[r] = 0.f;
    }
#pragma unroll
    for (int nt = 0; nt < 4; nt++)
#pragma unroll
      for (int r = 0; r < 4; r++) {
        float e = __expf(sv[nt][r] - m[r]);
        p[nt][r] = e;
        rs[r] += e;
      }
#pragma unroll
    for (int r = 0; r < 4; r++) {
#pragma unroll
      for (int off = 1; off < 16; off <<= 1)
        rs[r] += __shfl_xor(rs[r], off, 64);
      l[r] = l[r] * al[r] + rs[r];
    }
#pragma unroll
    for (int nt = 0; nt < 4; nt++)
#pragma unroll
      for (int r = 0; r < 4; r++) accO[nt][r] *= al[r];

    __syncthreads();
#pragma unroll
    for (int nt = 0; nt < 4; nt++)
#pragma unroll
      for (int r = 0; r < 4; r++)
        Ps[wv * 16 + quad * 4 + r][nt * 16 + l16] = f2bf(p[nt][r]);
    __syncthreads();

    short8 pf0 = *(const short8*)&Ps[wv * 16 + l16][quad * 8];
    short8 pf1 = *(const short8*)&Ps[wv * 16 + l16][32 + quad * 8];
#pragma unroll
    for (int nt = 0; nt < 4; nt++) {
      const u16* Vt = Vb + (size_t)(nt * 16 + l16) * 1024 + jt * 64;
      short8 v0 = *(const short8*)(Vt + quad * 8);
      short8 v1 = *(const short8*)(Vt + 32 + quad * 8);
      accO[nt] = __builtin_amdgcn_mfma_f32_16x16x32_bf16(pf0, v0, accO[nt], 0, 0, 0);
      accO[nt] = __builtin_amdgcn_mfma_f32_16x16x32_bf16(pf1, v1, accO[nt], 0, 0, 0);
    }
  }

  float inv[4];
#pragma unroll
  for (int r = 0; r < 4; r++) inv[r] = 1.f / l[r];
  __syncthreads();
#pragma unroll
  for (int nt = 0; nt < 4; nt++)
#pragma unroll
    for (int r = 0; r < 4; r++)
      Ps[wv * 16 + quad * 4 + r][nt * 16 + l16] = f2bf(accO[nt][r] * inv[r]);
  __syncthreads();
  int r = t >> 2, c0 = (t & 3) * 16;
  short8 o0 = *(const short8*)&Ps[r][c0];
  short8 o1 = *(const short8*)&Ps[r][c0 + 8];
  u16* dst = out + (size_t)(b * 1024 + qt * 64 + r) * 1024 + h * 64 + c0;
  *(short8*)dst = o0;
  *(short8*)(dst + 8) = o1;
}

// ---------------------------------------------------------------------------
// LayerNorm( xin + add ) * sc + bi  -> xout (f32) and xbf (bf16).
// ---------------------------------------------------------------------------
__global__ __launch_bounds__(256) void ln_kernel(
    const float* __restrict__ xin, const float* __restrict__ add,
    const float* __restrict__ sc, const float* __restrict__ bi,
    float* __restrict__ xout, u16* __restrict__ xbf)
{
  int row = blockIdx.x, t = threadIdx.x;
  float4 v = *(const float4*)(xin + (size_t)row * 1024 + t * 4);
  if (add) {
    float4 a = *(const float4*)(add + (size_t)row * 1024 + t * 4);
    v.x += a.x; v.y += a.y; v.z += a.z; v.w += a.w;
  }
  float s1 = v.x + v.y + v.z + v.w;
  float s2 = v.x * v.x + v.y * v.y + v.z * v.z + v.w * v.w;
#pragma unroll
  for (int off = 32; off > 0; off >>= 1) {
    s1 += __shfl_down(s1, off);
    s2 += __shfl_down(s2, off);
  }
  __shared__ float r1[4], r2[4];
  int lane = t & 63, wv = t >> 6;
  if (lane == 0) { r1[wv] = s1; r2[wv] = s2; }
  __syncthreads();
  float S1 = r1[0] + r1[1] + r1[2] + r1[3];
  float S2 = r2[0] + r2[1] + r2[2] + r2[3];
  float mn = S1 * (1.f / 1024.f);
  float var = S2 * (1.f / 1024.f) - mn * mn;
  float inv = rsqrtf(var + 1e-5f);
  float4 sv = *(const float4*)(sc + t * 4);
  float4 bv = *(const float4*)(bi + t * 4);
  float4 o;
  o.x = (v.x - mn) * inv * sv.x + bv.x;
  o.y = (v.y - mn) * inv * sv.y + bv.y;
  o.z = (v.z - mn) * inv * sv.z + bv.z;
  o.w = (v.w - mn) * inv * sv.w + bv.w;
  *(float4*)(xout + (size_t)row * 1024 + t * 4) = o;
  ushort4 ob; ob.x = f2bf(o.x); ob.y = f2bf(o.y); ob.z = f2bf(o.z); ob.w = f2bf(o.w);
  *(ushort4*)(xbf + (size_t)row * 1024 + t * 4) = ob;
}

// ---------------------------------------------------------------------------
// Final softmax: combine per-block partials (pass 1 fused into head GEMM),
// then one read+write pass over the logits.
// ---------------------------------------------------------------------------
__global__ __launch_bounds__(256) void softmax_final(
    float* __restrict__ out, const float2* __restrict__ partial, int pnb)
{
  int row = blockIdx.x, t = threadIdx.x;
  float m = -3.0e38f, s = 0.f;
  for (int j = t; j < pnb; j += 256) {
    float2 p = partial[(size_t)row * pnb + j];
    float mn = fmaxf(m, p.x);
    s = s * __expf(m - mn) + p.y * __expf(p.x - mn);
    m = mn;
  }
#pragma unroll
  for (int off = 32; off > 0; off >>= 1) {
    float m2 = __shfl_down(m, off), s2 = __shfl_down(s, off);
    float mn = fmaxf(m, m2);
    s = s * __expf(m - mn) + s2 * __expf(m2 - mn);
    m = mn;
  }
  __shared__ float rm[4], rs[4];
  int lane = t & 63, wv = t >> 6;
  if (lane == 0) { rm[wv] = m; rs[wv] = s; }
  __syncthreads();
  float M = rm[0], S = rs[0];
#pragma unroll
  for (int i = 1; i < 4; i++) {
    float mn = fmaxf(M, rm[i]);
    S = S * __expf(M - mn) + rs[i] * __expf(rm[i] - mn);
    M = mn;
  }
  float inv = 1.f / S;
  float4* p4 = (float4*)(out + (size_t)row * 32000);
  for (int j = t; j < 8000; j += 256) {
    float4 v = p4[j];
    v.x = __expf(v.x - M) * inv;
    v.y = __expf(v.y - M) * inv;
    v.z = __expf(v.z - M) * inv;
    v.w = __expf(v.w - M) * inv;
    p4[j] = v;
  }
}

// ---------------------------------------------------------------------------
// Launch
// ---------------------------------------------------------------------------
extern "C" void kernel_launch(void* const* d_in, const int* in_sizes, int n_in,
                              void* d_out, int out_size, void* d_ws, size_t ws_size,
                              hipStream_t stream)
{
  const int*   X       = (const int*)d_in[0];
  const float* tok_emb = (const float*)d_in[1];
  const float* pos_emb = (const float*)d_in[2];
  const float* qkv_w   = (const float*)d_in[3];
  const float* qkv_b   = (const float*)d_in[4];
  const float* out_w   = (const float*)d_in[5];
  const float* out_b   = (const float*)d_in[6];
  const float* ln1_s   = (const float*)d_in[7];
  const float* ln1_b   = (const float*)d_in[8];
  const float* ln2_s   = (const float*)d_in[9];
  const float* ln2_b   = (const float*)d_in[10];
  const float* ff1_w   = (const float*)d_in[11];
  const float* ff1_b   = (const float*)d_in[12];
  const float* ff2_w   = (const float*)d_in[13];
  const float* ff2_b   = (const float*)d_in[14];
  const float* lnf_s   = (const float*)d_in[15];
  const float* lnf_b   = (const float*)d_in[16];
  const float* head_w  = (const float*)d_in[17];
  const float* head_b  = (const float*)d_in[18];

  char* ws = (char*)d_ws;
  float* x      = (float*)ws;            ws += 2048ull * 1024 * 4;
  u16*   xbf    = (u16*)ws;              ws += 2048ull * 1024 * 2;
  u16*   qkvbuf = (u16*)ws;              ws += 2048ull * 3072 * 2;
  u16*   VTb    = (u16*)ws;              ws += 32ull * 64 * 1024 * 2;
  u16*   attnbf = (u16*)ws;              ws += 2048ull * 1024 * 2;
  float* tmp    = (float*)ws;            ws += 2048ull * 1024 * 4;
  u16*   hbf    = (u16*)ws;              ws += 2048ull * 4096 * 2;
  u16*   qkvT   = (u16*)ws;              ws += 3072ull * 1024 * 2;
  u16*   outT   = (u16*)ws;              ws += 1024ull * 1024 * 2;
  u16*   ff1T   = (u16*)ws;              ws += 4096ull * 1024 * 2;
  u16*   ff2T   = (u16*)ws;              ws += 1024ull * 4096 * 2;
  u16*   headT  = (u16*)ws;              ws += 32000ull * 1024 * 2;
  float2* smpart = (float2*)ws;          ws += 2048ull * 250 * 8;

  // all five weight transposes in one launch (block ranges inside)
  transpose_all<<<dim3(44288), 256, 0, stream>>>(
      qkv_w, qkvT, out_w, outT, ff1_w, ff1T, ff2_w, ff2T, head_w, headT);

  embed_kernel<<<2048, 256, 0, stream>>>(X, tok_emb, pos_emb, x, xbf);

  for (int l = 0; l < 6; l++) {
    // QKV GEMM with fused reshape: Q/K -> qkvbuf (bf16), V -> VTb (transposed)
    gemm_mfma<128, 2, 4, 4><<<dim3(3072 / 128, 2048 / 128), 256, 0, stream>>>(
        xbf, qkvT, qkv_b, qkvbuf, VTb, 2048, 3072, 1024, 4);
    flash_attn<<<dim3(16, 16, 2), 256, 0, stream>>>(qkvbuf, VTb, attnbf);
    // proj: BN=64 tiles -> 512 wg = 2 blocks/CU
    gemm_mfma<64, 4, 4, 1><<<dim3(1024 / 64, 2048 / 64), 256, 0, stream>>>(
        attnbf, outT, out_b, tmp, nullptr, 2048, 1024, 1024, 0);
    ln_kernel<<<2048, 256, 0, stream>>>(x, tmp, ln1_s, ln1_b, x, xbf);
    gemm_mfma<128, 2, 4, 4><<<dim3(4096 / 128, 2048 / 128), 256, 0, stream>>>(
        xbf, ff1T, ff1_b, hbf, nullptr, 2048, 4096, 1024, 1);
    // ff2: BN=64 tiles -> 512 wg = 2 blocks/CU (K=4096: 64 staging steps)
    gemm_mfma<64, 4, 4, 1><<<dim3(1024 / 64, 2048 / 64), 256, 0, stream>>>(
        hbf, ff2T, ff2_b, tmp, nullptr, 2048, 1024, 4096, 0);
    ln_kernel<<<2048, 256, 0, stream>>>(x, tmp, ln2_s, ln2_b, x, xbf);
  }

  ln_kernel<<<2048, 256, 0, stream>>>(x, nullptr, lnf_s, lnf_b, x, xbf);
  // head GEMM: 8-phase 256^2 (R5-verified 196.9us) + fused softmax pass-1
  gemm_256_8ph<<<dim3(32000 / 256, 2048 / 256), 512, 0, stream>>>(
      xbf, headT, head_b, (float*)d_out, smpart, 2048, 32000, 1024, 2);
  softmax_final<<<2048, 256, 0, stream>>>((float*)d_out, smpart, 125);
}